// Round 7
// baseline (209.744 us; speedup 1.0000x reference)
//
#include <hip/hip_runtime.h>
#include <stdint.h>

// B=2, T=2048, C=1024, H=16, HD=64
// qkv ws layout: [3][B*H=32][T=2048][HD=64] bf16 (v region unused); vt: [32][64][2048] bf16

typedef short bf16x8 __attribute__((ext_vector_type(8)));
typedef float f32x4 __attribute__((ext_vector_type(4)));

__device__ inline unsigned short f2bf(float f) {
  union { float f; uint32_t u; } v; v.f = f;
  uint32_t u = v.u;
  u += 0x7FFFu + ((u >> 16) & 1u);   // round-to-nearest-even
  return (unsigned short)(u >> 16);
}

// pack two fp32 -> two bf16 in one dword — HW instruction (no builtin on gfx950, m240)
__device__ inline unsigned pkbf(float a, float b) {
  unsigned r;
  asm("v_cvt_pk_bf16_f32 %0, %1, %2" : "=v"(r) : "v"(a), "v"(b));
  return r;
}

// raw v_exp_f32 (2^x) without OCML range fixup; inputs bounded, -3e38 -> +0
__device__ inline float exp2_fast(float x) {
#if __has_builtin(__builtin_amdgcn_exp2f)
  return __builtin_amdgcn_exp2f(x);
#else
  float r; asm("v_exp_f32 %0, %1" : "=v"(r) : "v"(x)); return r;
#endif
}

// async global->LDS, 16B per lane, dest = lds base + lane*16
__device__ inline void load_lds16(const unsigned short* g, unsigned short* l) {
  __builtin_amdgcn_global_load_lds(
      (const __attribute__((address_space(1))) unsigned int*)(const void*)g,
      (__attribute__((address_space(3))) unsigned int*)(void*)l, 16, 0, 0);
}

// ---------- fused prep: cast x -> bf16, transpose+cast w_attn, w_proj ----------
// blocks [0,4096): cast 1048576 float4 of x
// blocks [4096,7168): transpose w_attn [1024][3072] -> [3072][1024]
// blocks [7168,8192): transpose w_proj [1024][1024] -> [1024][1024]
__global__ __launch_bounds__(256) void prep_kernel(
    const float* __restrict__ x, const float* __restrict__ w_attn,
    const float* __restrict__ w_proj,
    unsigned short* __restrict__ xb, unsigned short* __restrict__ wattnT,
    unsigned short* __restrict__ wprojT) {
  __shared__ float tile[32][33];
  const int b = blockIdx.x, t = threadIdx.x;
  if (b < 4096) {
    int i = b * 256 + t;                      // < 1048576 always
    float4 f = reinterpret_cast<const float4*>(x)[i];
    ushort4 o;
    o.x = f2bf(f.x); o.y = f2bf(f.y); o.z = f2bf(f.z); o.w = f2bf(f.w);
    reinterpret_cast<ushort4*>(xb)[i] = o;
    return;
  }
  const float* in; unsigned short* out; int R, Cn, bx, by;
  if (b < 7168) {
    int bb = b - 4096;
    in = w_attn; out = wattnT; R = 1024; Cn = 3072;
    bx = (bb % 96) * 32; by = (bb / 96) * 32;
  } else {
    int bb = b - 7168;
    in = w_proj; out = wprojT; R = 1024; Cn = 1024;
    bx = (bb % 32) * 32; by = (bb / 32) * 32;
  }
  const int tx = t & 31, ty = t >> 5;         // block acts as (32,8)
  #pragma unroll
  for (int i = 0; i < 32; i += 8)
    tile[ty + i][tx] = in[(size_t)(by + ty + i) * Cn + bx + tx];
  __syncthreads();
  #pragma unroll
  for (int i = 0; i < 32; i += 8)
    out[(size_t)(bx + ty + i) * R + by + tx] = f2bf(tile[tx][ty + i]);
}

// ---------- bf16 MFMA GEMM: C[M,N] = A[M,K] * Bt[N,K]^T + bias ----------
// Slot-amortization structure: time = chains/CU x 32 slots x ~1150cy, so maximize
// MFMA per slot and make grid = exact multiple of CU capacity.
// QKV: 128x192 tile (N=3072=16x192!) -> grid 512 = 2 blocks/CU (RF: ~166 regs ->
// 8 waves/CU), 24 MFMA/slot/wave (1.5x the 128^2 config), 64 slots/CU (was 96).
// Schedule (round-3 proven): 2 LDS buffers, ONE barrier per K-step, vmcnt(0):
//   iter kt: vmcnt(0) [own tile-kt DMAs done]; barrier [all waves' DMAs done AND
//   buf^1's old tile consumed by everyone]; stage(kt+1 -> buf^1); compute(kt).
// Unpadded BMx32-short tiles, chunk swizzle pos = c ^ ((row>>1)&3).
// mode 0: write fp32 to out [M,N]
// mode 1: QKV scatter: q/k -> qkv layout (q scaled by 0.125*log2e), v -> vt[bh][d][t]
template<int BM, int BN>
__global__ __launch_bounds__(256) void gemm_bt_kernel(
    const unsigned short* __restrict__ A,
    const unsigned short* __restrict__ Bt,
    const float* __restrict__ bias,
    void* __restrict__ outp,
    unsigned short* __restrict__ vtp,
    int M, int N, int K, int mode) {
  constexpr int MT = BM / 32, NT = BN / 32;   // frags per wave per dim (2x2 wave grid)
  constexpr int RPWA = BM / 4, RPWB = BN / 4; // staged rows per wave
  constexpr int NJA = RPWA / 16, NJB = RPWB / 16;
  static_assert(NJA >= 1 && NJB >= 1, "need >=16 staged rows per wave");
  __shared__ unsigned short As[2][BM * 32];
  __shared__ unsigned short Bs[2][BN * 32];
  const int t = threadIdx.x;
  const int wave = t >> 6, lane = t & 63;
  const int L = lane & 15, quad = lane >> 4;
  const int wm = (wave >> 1) * (BM / 2), wn = (wave & 1) * (BN / 2);
  const int m0 = blockIdx.y * BM, n0 = blockIdx.x * BN;

  // DMA per-lane source mapping: 16 rows per instr, lane>>2 = row, lane&3 = stored pos
  const int drow = lane >> 2;
  const int dch  = (lane & 3) ^ ((drow >> 1) & 3);
  // frag read: logical chunk `quad` of row L stored at quad ^ ((L>>1)&3)
  const int foff = ((quad ^ ((L >> 1) & 3)) * 8);

  const unsigned short* Ab = A  + (size_t)(m0 + wave * RPWA + drow) * K + dch * 8;
  const unsigned short* Bb = Bt + (size_t)(n0 + wave * RPWB + drow) * K + dch * 8;

  f32x4 acc[MT][NT] = {};
  const int NK = K >> 5;

  // prologue: stage tile 0 -> buf 0
  #pragma unroll
  for (int j = 0; j < NJA; ++j)
    load_lds16(Ab + (size_t)j * 16 * K, &As[0][(wave * RPWA + j * 16) * 32]);
  #pragma unroll
  for (int j = 0; j < NJB; ++j)
    load_lds16(Bb + (size_t)j * 16 * K, &Bs[0][(wave * RPWB + j * 16) * 32]);

  int buf = 0;
  for (int kt = 0; kt < NK; ++kt) {
    asm volatile("" ::: "memory");
    __builtin_amdgcn_s_waitcnt(0x0F70);   // vmcnt(0): own DMAs for tile kt landed
    __builtin_amdgcn_s_barrier();         // everyone's DMAs landed; buf^1 consumed
    asm volatile("" ::: "memory");

    if (kt + 1 < NK) {                    // stage kt+1 into the other buffer
      #pragma unroll
      for (int j = 0; j < NJA; ++j)
        load_lds16(Ab + (size_t)j * 16 * K + (kt + 1) * 32,
                   &As[buf ^ 1][(wave * RPWA + j * 16) * 32]);
      #pragma unroll
      for (int j = 0; j < NJB; ++j)
        load_lds16(Bb + (size_t)j * 16 * K + (kt + 1) * 32,
                   &Bs[buf ^ 1][(wave * RPWB + j * 16) * 32]);
    }

    bf16x8 af[MT], bf[NT];
    #pragma unroll
    for (int mt = 0; mt < MT; ++mt)
      af[mt] = *reinterpret_cast<const bf16x8*>(&As[buf][(wm + mt * 16 + L) * 32 + foff]);
    #pragma unroll
    for (int nt = 0; nt < NT; ++nt)
      bf[nt] = *reinterpret_cast<const bf16x8*>(&Bs[buf][(wn + nt * 16 + L) * 32 + foff]);
    __builtin_amdgcn_s_setprio(1);
    #pragma unroll
    for (int mt = 0; mt < MT; ++mt)
      #pragma unroll
      for (int nt = 0; nt < NT; ++nt)
        acc[mt][nt] = __builtin_amdgcn_mfma_f32_16x16x32_bf16(af[mt], bf[nt], acc[mt][nt], 0, 0, 0);
    __builtin_amdgcn_s_setprio(0);
    buf ^= 1;
  }

  if (mode == 0) {
    float* out = (float*)outp;
    #pragma unroll
    for (int mt = 0; mt < MT; ++mt)
      #pragma unroll
      for (int nt = 0; nt < NT; ++nt) {
        int col = n0 + wn + nt * 16 + L;
        float b = bias[col];
        #pragma unroll
        for (int r = 0; r < 4; ++r) {
          int row = m0 + wm + mt * 16 + quad * 4 + r;
          out[(size_t)row * N + col] = acc[mt][nt][r] + b;
        }
      }
  } else {
    unsigned short* qkv = (unsigned short*)outp;  // [3][32][2048][64]
    #pragma unroll
    for (int mt = 0; mt < MT; ++mt)
      #pragma unroll
      for (int nt = 0; nt < NT; ++nt) {
        int col = n0 + wn + nt * 16 + L;          // 0..3071
        int sel = col >> 10, cc = col & 1023;
        int h = cc >> 6, d = cc & 63;
        float b = bias[col];
        // fold 1/sqrt(64) * log2(e) into q so attention uses exp2 directly
        float sc = (sel == 0) ? 0.18033688011112042f : 1.0f;
        #pragma unroll
        for (int r = 0; r < 4; ++r) {
          int row = m0 + wm + mt * 16 + quad * 4 + r;  // 0..4095
          int bb = row >> 11, tt = row & 2047;
          float val = (acc[mt][nt][r] + b) * sc;
          if (sel == 2) {
            // v -> vt[bh][d][t]  (fused V transpose)
            vtp[((size_t)(bb * 16 + h) * 64 + d) * 2048 + tt] = f2bf(val);
          } else {
            qkv[(((size_t)sel * 32 + (size_t)(bb * 16 + h)) * 2048 + tt) * 64 + d] = f2bf(val);
          }
        }
      }
  }
}

// ---------- flash attention v5 (round-1/3 best-measured config) ----------
// Softmax VALU diet: HW v_cvt_pk_bf16_f32, raw v_exp_f32, setprio around MFMA.
// Pair fold-balance + XCD-aware decode: all 16 pair-blocks of a bh share one mod-8
// residue class -> same XCD L2 caches that bh's K/V (cuts HBM re-fetch ~8x).
// S^T via swapped MFMA operands; 3-buffer K/V pipeline, single barrier per tile.
__global__ __launch_bounds__(256) void attn_kernel(
    const unsigned short* __restrict__ qkv,
    const unsigned short* __restrict__ vt,
    unsigned short* __restrict__ y) {
  __shared__ unsigned short Ks[3][64 * 64];  // [key][d], swizzled chunks
  __shared__ unsigned short Vs[3][64 * 64];  // [d][key], swizzled chunks
  __shared__ unsigned short Ps[4][32][72];   // per-wave P[qrow][key]: rows 0-15 A, 16-31 B

  const int t = threadIdx.x;
  const int wave = t >> 6, lane = t & 63;
  const int L = lane & 15, quad = lane >> 4;
  // XCD-aware decode: residue class (b&7) -> XCD; 4 bh per class x 16 pairs
  const int b = blockIdx.x;
  const int bh = (b & 7) * 4 + ((b >> 3) & 3);
  const int pi = b >> 5;                // pair index 0..15
  const int tA = pi, tB = 31 - pi;      // 64-row q-tile indices
  const int rowA0 = tA * 64 + wave * 16;
  const int rowB0 = tB * 64 + wave * 16;
  const int ntiles = tB + 1;

  const unsigned short* qb  = qkv + ((size_t)bh * 2048) * 64;
  const unsigned short* kb  = qkv + ((size_t)(32 + bh) * 2048) * 64;
  const unsigned short* vtb = vt + (size_t)bh * 64 * 2048;

  // DMA per-lane constants: 8 rows (128B each) per instruction
  const int drow = lane >> 3;           // 0..7
  const int dch  = (lane & 7) ^ drow;   // source chunk (xor swizzle)
  // frag-read swizzle offsets: chunk c of row r stored at c^(r&7)
  const int fo0 = ((quad ^ (L & 7)) * 8);
  const int fo1 = (((quad + 4) ^ (L & 7)) * 8);

  // Q fragments (A/B-operand layout, direct from global, resident all kernel)
  bf16x8 qfA[2], qfB[2];
  #pragma unroll
  for (int h = 0; h < 2; ++h) {
    qfA[h] = *reinterpret_cast<const bf16x8*>(qb + (size_t)(rowA0 + L) * 64 + h * 32 + quad * 8);
    qfB[h] = *reinterpret_cast<const bf16x8*>(qb + (size_t)(rowB0 + L) * 64 + h * 32 + quad * 8);
  }

  f32x4 oA[4] = {}, oB[4] = {};
  float rsA = 0.f, rsB = 0.f;

  // prologue: stage tile 0 -> buf 0 (4 DMA instrs per wave per stage)
  {
    #pragma unroll
    for (int j = 0; j < 2; ++j) {
      int r0 = wave * 16 + j * 8;
      load_lds16(kb  + (size_t)(0 + r0 + drow) * 64 + dch * 8, &Ks[0][r0 * 64]);
      load_lds16(vtb + (size_t)(r0 + drow) * 2048 + 0 + dch * 8, &Vs[0][r0 * 64]);
    }
  }

  int buf = 0;
  for (int kt = 0; kt < ntiles; ++kt) {
    // stage kt+1 (clamped dummy on last iter keeps vmcnt accounting uniform)
    const int nkt = (kt + 1 < ntiles) ? kt + 1 : ntiles - 1;
    const int nbuf = (buf == 2) ? 0 : buf + 1;
    {
      const int kg = nkt * 64;
      #pragma unroll
      for (int j = 0; j < 2; ++j) {
        int r0 = wave * 16 + j * 8;
        load_lds16(kb  + (size_t)(kg + r0 + drow) * 64 + dch * 8, &Ks[nbuf][r0 * 64]);
        load_lds16(vtb + (size_t)(r0 + drow) * 2048 + kg + dch * 8, &Vs[nbuf][r0 * 64]);
      }
    }
    asm volatile("" ::: "memory");
    __builtin_amdgcn_s_waitcnt(0x0F74);   // vmcnt(4): tile kt's 4 DMAs done; kt+1 in flight
    __builtin_amdgcn_s_barrier();
    asm volatile("" ::: "memory");

    const bool actA = (kt <= tA);

    // ---- S^T = K Q^T : D[m=key][n=qrow] (A=K-frag, B=Q-frag) ----
    bf16x8 kf[4][2];
    #pragma unroll
    for (int nt = 0; nt < 4; ++nt) {
      kf[nt][0] = *reinterpret_cast<const bf16x8*>(&Ks[buf][(nt * 16 + L) * 64 + fo0]);
      kf[nt][1] = *reinterpret_cast<const bf16x8*>(&Ks[buf][(nt * 16 + L) * 64 + fo1]);
    }

    f32x4 sB[4] = {};
    __builtin_amdgcn_s_setprio(1);
    #pragma unroll
    for (int nt = 0; nt < 4; ++nt) {
      sB[nt] = __builtin_amdgcn_mfma_f32_16x16x32_bf16(kf[nt][0], qfB[0], sB[nt], 0, 0, 0);
      sB[nt] = __builtin_amdgcn_mfma_f32_16x16x32_bf16(kf[nt][1], qfB[1], sB[nt], 0, 0, 0);
    }
    __builtin_amdgcn_s_setprio(0);
    if (kt == tB) {  // diagonal mask: key > qrow -> -inf
      #pragma unroll
      for (int nt = 0; nt < 4; ++nt) {
        int key0 = kt * 64 + nt * 16 + quad * 4;
        int qr = rowB0 + L;
        #pragma unroll
        for (int r = 0; r < 4; ++r)
          if (key0 + r > qr) sB[nt][r] = -3.0e38f;
      }
    }
    #pragma unroll
    for (int nt = 0; nt < 4; ++nt) {
      float p0 = exp2_fast(sB[nt][0]), p1 = exp2_fast(sB[nt][1]);
      float p2 = exp2_fast(sB[nt][2]), p3 = exp2_fast(sB[nt][3]);
      rsB += (p0 + p1) + (p2 + p3);
      uint2 pk;
      pk.x = pkbf(p0, p1);
      pk.y = pkbf(p2, p3);
      *reinterpret_cast<uint2*>(&Ps[wave][16 + L][nt * 16 + quad * 4]) = pk;
    }

    if (actA) {
      f32x4 sA[4] = {};
      __builtin_amdgcn_s_setprio(1);
      #pragma unroll
      for (int nt = 0; nt < 4; ++nt) {
        sA[nt] = __builtin_amdgcn_mfma_f32_16x16x32_bf16(kf[nt][0], qfA[0], sA[nt], 0, 0, 0);
        sA[nt] = __builtin_amdgcn_mfma_f32_16x16x32_bf16(kf[nt][1], qfA[1], sA[nt], 0, 0, 0);
      }
      __builtin_amdgcn_s_setprio(0);
      if (kt == tA) {
        #pragma unroll
        for (int nt = 0; nt < 4; ++nt) {
          int key0 = kt * 64 + nt * 16 + quad * 4;
          int qr = rowA0 + L;
          #pragma unroll
          for (int r = 0; r < 4; ++r)
            if (key0 + r > qr) sA[nt][r] = -3.0e38f;
        }
      }
      #pragma unroll
      for (int nt = 0; nt < 4; ++nt) {
        float p0 = exp2_fast(sA[nt][0]), p1 = exp2_fast(sA[nt][1]);
        float p2 = exp2_fast(sA[nt][2]), p3 = exp2_fast(sA[nt][3]);
        rsA += (p0 + p1) + (p2 + p3);
        uint2 pk;
        pk.x = pkbf(p0, p1);
        pk.y = pkbf(p2, p3);
        *reinterpret_cast<uint2*>(&Ps[wave][L][nt * 16 + quad * 4]) = pk;
      }
    }

    // ---- O += P V ----  (P in A-layout directly from Ps[qrow][key])
    bf16x8 vf[4][2];
    #pragma unroll
    for (int nt = 0; nt < 4; ++nt) {
      vf[nt][0] = *reinterpret_cast<const bf16x8*>(&Vs[buf][(nt * 16 + L) * 64 + fo0]);
      vf[nt][1] = *reinterpret_cast<const bf16x8*>(&Vs[buf][(nt * 16 + L) * 64 + fo1]);
    }
    bf16x8 pb0 = *reinterpret_cast<const bf16x8*>(&Ps[wave][16 + L][quad * 8]);
    bf16x8 pb1 = *reinterpret_cast<const bf16x8*>(&Ps[wave][16 + L][32 + quad * 8]);
    __builtin_amdgcn_s_setprio(1);
    #pragma unroll
    for (int nt = 0; nt < 4; ++nt) {
      oB[nt] = __builtin_amdgcn_mfma_f32_16x16x32_bf16(pb0, vf[nt][0], oB[nt], 0, 0, 0);
      oB[nt] = __builtin_amdgcn_mfma_f32_16x16x32_bf16(pb1, vf[nt][1], oB[nt], 0, 0, 0);
    }
    __builtin_amdgcn_s_setprio(0);
    if (actA) {
      bf16x8 pa0 = *reinterpret_cast<const bf16x8*>(&Ps[wave][L][quad * 8]);
      bf16x8 pa1 = *reinterpret_cast<const bf16x8*>(&Ps[wave][L][32 + quad * 8]);
      __builtin_amdgcn_s_setprio(1);
      #pragma unroll
      for (int nt = 0; nt < 4; ++nt) {
        oA[nt] = __builtin_amdgcn_mfma_f32_16x16x32_bf16(pa0, vf[nt][0], oA[nt], 0, 0, 0);
        oA[nt] = __builtin_amdgcn_mfma_f32_16x16x32_bf16(pa1, vf[nt][1], oA[nt], 0, 0, 0);
      }
      __builtin_amdgcn_s_setprio(0);
    }
    buf = nbuf;
  }

  // ---- epilogue: reduce l across quads (rows live on L), fetch per-output-row via shfl ----
  float a = rsA; a += __shfl_xor(a, 16, 64); a += __shfl_xor(a, 32, 64);
  float b2 = rsB; b2 += __shfl_xor(b2, 16, 64); b2 += __shfl_xor(b2, 32, 64);
  float invA[4], invB[4];
  #pragma unroll
  for (int r = 0; r < 4; ++r) {
    invA[r] = 1.0f / __shfl(a, quad * 4 + r, 64);
    invB[r] = 1.0f / __shfl(b2, quad * 4 + r, 64);
  }
  const int bb = bh >> 4, hh = bh & 15;
  #pragma unroll
  for (int nt = 0; nt < 4; ++nt)
    #pragma unroll
    for (int r = 0; r < 4; ++r) {
      int rA = rowA0 + quad * 4 + r;
      int rB = rowB0 + quad * 4 + r;
      int col = hh * 64 + nt * 16 + L;
      y[((size_t)bb * 2048 + rA) * 1024 + col] = f2bf(oA[nt][r] * invA[r]);
      y[((size_t)bb * 2048 + rB) * 1024 + col] = f2bf(oB[nt][r] * invB[r]);
    }
  // drain outstanding dummy DMAs before LDS dealloc at wave end
  __builtin_amdgcn_s_waitcnt(0);
}

extern "C" void kernel_launch(void* const* d_in, const int* in_sizes, int n_in,
                              void* d_out, int out_size, void* d_ws, size_t ws_size,
                              hipStream_t stream) {
  const float* x      = (const float*)d_in[0];  // [2,2048,1024]
  const float* w_attn = (const float*)d_in[1];  // [1024,3072]
  const float* b_attn = (const float*)d_in[2];  // [3072]
  const float* w_proj = (const float*)d_in[3];  // [1024,1024]
  const float* b_proj = (const float*)d_in[4];  // [1024]
  float* out = (float*)d_out;                   // [2,2048,1024] fp32

  unsigned short* ws = (unsigned short*)d_ws;
  unsigned short* xb     = ws;                    //  4194304 [4096,1024]
  unsigned short* wattnT = xb + 4194304;          //  3145728 [3072,1024]
  unsigned short* wprojT = wattnT + 3145728;      //  1048576 [1024,1024]
  unsigned short* qkv    = wprojT + 1048576;      // 12582912 [3][32][2048][64] (v unused)
  unsigned short* yb     = qkv + 12582912;        //  4194304 [4096,1024]
  unsigned short* vt     = yb + 4194304;          //  4194304 [32][64][2048]

  // fused prep: cast x + transpose both weight matrices (one launch)
  prep_kernel<<<8192, 256, 0, stream>>>(x, w_attn, w_proj, xb, wattnT, wprojT);

  // QKV: M=4096, N=3072, K=1024; 128x192 tiles -> grid 512 = exactly 2 blocks/CU,
  // 24 MFMA/slot/wave, 64 sync slots per CU (was 96 at 128^2 x 3/CU)
  gemm_bt_kernel<128, 192><<<dim3(16, 32), 256, 0, stream>>>(xb, wattnT, b_attn, qkv, vt, 4096, 3072, 1024, 1);
  // attention (fold-balanced, XCD-grouped, 3-buffer pipelined)
  attn_kernel<<<dim3(512), 256, 0, stream>>>(qkv, vt, yb);
  // proj: M=4096, N=1024, K=1024; 64^2 tiles (round-3 config)
  gemm_bt_kernel<64, 64><<<dim3(16, 64), 256, 0, stream>>>(yb, wprojT, b_proj, out, nullptr, 4096, 1024, 1024, 0);
}

// Round 8
// 192.465 us; speedup vs baseline: 1.0898x; 1.0898x over previous
//
#include <hip/hip_runtime.h>
#include <stdint.h>

// B=2, T=2048, C=1024, H=16, HD=64
// qkv ws layout: [3][B*H=32][T=2048][HD=64] bf16 (v region unused); vt: [32][64][2048] bf16

typedef short bf16x8 __attribute__((ext_vector_type(8)));
typedef float f32x4 __attribute__((ext_vector_type(4)));

__device__ inline unsigned short f2bf(float f) {
  union { float f; uint32_t u; } v; v.f = f;
  uint32_t u = v.u;
  u += 0x7FFFu + ((u >> 16) & 1u);   // round-to-nearest-even
  return (unsigned short)(u >> 16);
}

// pack two fp32 -> two bf16 in one dword — HW instruction (no builtin on gfx950, m240)
__device__ inline unsigned pkbf(float a, float b) {
  unsigned r;
  asm("v_cvt_pk_bf16_f32 %0, %1, %2" : "=v"(r) : "v"(a), "v"(b));
  return r;
}

// raw v_exp_f32 (2^x) without OCML range fixup; inputs bounded, -3e38 -> +0
__device__ inline float exp2_fast(float x) {
#if __has_builtin(__builtin_amdgcn_exp2f)
  return __builtin_amdgcn_exp2f(x);
#else
  float r; asm("v_exp_f32 %0, %1" : "=v"(r) : "v"(x)); return r;
#endif
}

// async global->LDS, 16B per lane, dest = lds base + lane*16
__device__ inline void load_lds16(const unsigned short* g, unsigned short* l) {
  __builtin_amdgcn_global_load_lds(
      (const __attribute__((address_space(1))) unsigned int*)(const void*)g,
      (__attribute__((address_space(3))) unsigned int*)(void*)l, 16, 0, 0);
}

// ---------- fused prep: cast x -> bf16, transpose+cast w_attn, w_proj ----------
// blocks [0,4096): cast 1048576 float4 of x
// blocks [4096,7168): transpose w_attn [1024][3072] -> [3072][1024]
// blocks [7168,8192): transpose w_proj [1024][1024] -> [1024][1024]
__global__ __launch_bounds__(256) void prep_kernel(
    const float* __restrict__ x, const float* __restrict__ w_attn,
    const float* __restrict__ w_proj,
    unsigned short* __restrict__ xb, unsigned short* __restrict__ wattnT,
    unsigned short* __restrict__ wprojT) {
  __shared__ float tile[32][33];
  const int b = blockIdx.x, t = threadIdx.x;
  if (b < 4096) {
    int i = b * 256 + t;                      // < 1048576 always
    float4 f = reinterpret_cast<const float4*>(x)[i];
    ushort4 o;
    o.x = f2bf(f.x); o.y = f2bf(f.y); o.z = f2bf(f.z); o.w = f2bf(f.w);
    reinterpret_cast<ushort4*>(xb)[i] = o;
    return;
  }
  const float* in; unsigned short* out; int R, Cn, bx, by;
  if (b < 7168) {
    int bb = b - 4096;
    in = w_attn; out = wattnT; R = 1024; Cn = 3072;
    bx = (bb % 96) * 32; by = (bb / 96) * 32;
  } else {
    int bb = b - 7168;
    in = w_proj; out = wprojT; R = 1024; Cn = 1024;
    bx = (bb % 32) * 32; by = (bb / 32) * 32;
  }
  const int tx = t & 31, ty = t >> 5;         // block acts as (32,8)
  #pragma unroll
  for (int i = 0; i < 32; i += 8)
    tile[ty + i][tx] = in[(size_t)(by + ty + i) * Cn + bx + tx];
  __syncthreads();
  #pragma unroll
  for (int i = 0; i < 32; i += 8)
    out[(size_t)(bx + ty + i) * R + by + tx] = f2bf(tile[tx][ty + i]);
}

// ---------- QKV GEMM, phase-split schedule (T3-style) ----------
// M=4096 N=3072 K=1024 fixed. Tile 256x192 -> grid 16x16 = 256 blocks = EXACTLY
// 1 block/CU. 8 waves (2Mx4N), per-wave 128x48 (acc[8][3] = 96 AGPR, ~175 regs
// -> 2 waves/SIMD -> whole block resident). BK=64, 2 LDS buffers (112 KB).
// Per K-tile: vmcnt(0)+barrier (tile landed, buf^1 free), then 4 phases:
//   phase 0: issue ALL 7 next-tile global_load_lds (into buf^1) + ds_read bf[2][3]
//            + af pair; phases 1-3: ds_read af pair.
//   each phase: barrier; setprio(1); 12 MFMA; setprio(0); barrier.
// The tile-top vmcnt(0) thus waits on loads issued ~3.5 phases (~full K-tile) ago
// — latency cover by construction, no dummy-load accounting.
// 64-wide-row chunk swizzle (round-6-verified): store pos of chunk c, row r =
// c^(r&7); frag chunk q of row L at (q^(L&7)).
// Epilogue: QKV scatter q/k -> qkv layout (q scaled by 0.125*log2e), v -> vt[bh][d][t].
__global__ __launch_bounds__(512) void gemm_qkv_kernel(
    const unsigned short* __restrict__ A,
    const unsigned short* __restrict__ Bt,
    const float* __restrict__ bias,
    unsigned short* __restrict__ qkv,
    unsigned short* __restrict__ vtp) {
  constexpr int K = 1024;
  __shared__ unsigned short As[2][256 * 64];   // 64 KB
  __shared__ unsigned short Bs[2][192 * 64];   // 48 KB
  const int t = threadIdx.x;
  const int wave = t >> 6, lane = t & 63;
  const int L = lane & 15, quad = lane >> 4;
  const int wm = (wave >> 2) * 128, wn = (wave & 3) * 48;
  const int m0 = blockIdx.y * 256, n0 = blockIdx.x * 192;

  // DMA per-lane mapping: 8 rows (128B each) per instruction
  const int drow = lane >> 3;           // 0..7
  const int dch  = (lane & 7) ^ drow;   // source chunk (xor swizzle)
  // frag-read swizzle offsets: chunk c of row r stored at c^(r&7)
  const int fo0 = ((quad ^ (L & 7)) * 8);
  const int fo1 = (((quad + 4) ^ (L & 7)) * 8);

  const unsigned short* Ab = A  + (size_t)(m0 + wave * 32 + drow) * K + dch * 8;
  const unsigned short* Bb = Bt + (size_t)(n0 + wave * 24 + drow) * K + dch * 8;

  f32x4 acc[8][3] = {};

  // prologue: stage K-tile 0 -> buf 0 (4 A + 3 B instrs per wave)
  #pragma unroll
  for (int j = 0; j < 4; ++j)
    load_lds16(Ab + (size_t)j * 8 * K, &As[0][(wave * 32 + j * 8) * 64]);
  #pragma unroll
  for (int j = 0; j < 3; ++j)
    load_lds16(Bb + (size_t)j * 8 * K, &Bs[0][(wave * 24 + j * 8) * 64]);

  for (int kt = 0; kt < 16; ++kt) {
    const int cur = kt & 1;
    asm volatile("" ::: "memory");
    __builtin_amdgcn_s_waitcnt(0x0F70);   // vmcnt(0): tile kt landed (issued ~1 tile ago)
    __builtin_amdgcn_s_barrier();         // all waves' DMAs landed; buf^1 consumed
    asm volatile("" ::: "memory");

    bf16x8 bf[2][3];
    #pragma unroll
    for (int p = 0; p < 4; ++p) {
      if (p == 0) {
        // issue the ENTIRE next-tile stage now -> max issue-to-wait distance
        if (kt + 1 < 16) {
          #pragma unroll
          for (int j = 0; j < 4; ++j)
            load_lds16(Ab + (size_t)j * 8 * K + (size_t)(kt + 1) * 64,
                       &As[cur ^ 1][(wave * 32 + j * 8) * 64]);
          #pragma unroll
          for (int j = 0; j < 3; ++j)
            load_lds16(Bb + (size_t)j * 8 * K + (size_t)(kt + 1) * 64,
                       &Bs[cur ^ 1][(wave * 24 + j * 8) * 64]);
        }
        #pragma unroll
        for (int nt = 0; nt < 3; ++nt) {
          bf[0][nt] = *reinterpret_cast<const bf16x8*>(&Bs[cur][(wn + nt * 16 + L) * 64 + fo0]);
          bf[1][nt] = *reinterpret_cast<const bf16x8*>(&Bs[cur][(wn + nt * 16 + L) * 64 + fo1]);
        }
      }
      bf16x8 af[2][2];
      #pragma unroll
      for (int h = 0; h < 2; ++h) {
        const int mt = 2 * p + h;
        af[h][0] = *reinterpret_cast<const bf16x8*>(&As[cur][(wm + mt * 16 + L) * 64 + fo0]);
        af[h][1] = *reinterpret_cast<const bf16x8*>(&As[cur][(wm + mt * 16 + L) * 64 + fo1]);
      }
      asm volatile("" ::: "memory");
      __builtin_amdgcn_s_barrier();       // align waves: reads issued before MFMA burst
      __builtin_amdgcn_s_setprio(1);
      #pragma unroll
      for (int h = 0; h < 2; ++h)
        #pragma unroll
        for (int nt = 0; nt < 3; ++nt) {
          acc[2 * p + h][nt] = __builtin_amdgcn_mfma_f32_16x16x32_bf16(af[h][0], bf[0][nt], acc[2 * p + h][nt], 0, 0, 0);
          acc[2 * p + h][nt] = __builtin_amdgcn_mfma_f32_16x16x32_bf16(af[h][1], bf[1][nt], acc[2 * p + h][nt], 0, 0, 0);
        }
      __builtin_amdgcn_s_setprio(0);
      asm volatile("" ::: "memory");
      __builtin_amdgcn_s_barrier();
    }
  }

  // epilogue: QKV scatter (q scaled by 0.125*log2e folded in; v -> vt transpose)
  #pragma unroll
  for (int mt = 0; mt < 8; ++mt)
    #pragma unroll
    for (int nt = 0; nt < 3; ++nt) {
      int col = n0 + wn + nt * 16 + L;          // 0..3071
      int sel = col >> 10, cc = col & 1023;
      int h = cc >> 6, d = cc & 63;
      float b = bias[col];
      float sc = (sel == 0) ? 0.18033688011112042f : 1.0f;
      #pragma unroll
      for (int r = 0; r < 4; ++r) {
        int row = m0 + wm + mt * 16 + quad * 4 + r;  // 0..4095
        int bb = row >> 11, tt = row & 2047;
        float val = (acc[mt][nt][r] + b) * sc;
        if (sel == 2) {
          vtp[((size_t)(bb * 16 + h) * 64 + d) * 2048 + tt] = f2bf(val);
        } else {
          qkv[(((size_t)sel * 32 + (size_t)(bb * 16 + h)) * 2048 + tt) * 64 + d] = f2bf(val);
        }
      }
    }
}

// ---------- bf16 MFMA GEMM, BK=32 (proj; round-3 proven config) ----------
// 2 LDS buffers, ONE barrier per K-step, vmcnt(0). Unpadded BMx32-short tiles,
// chunk swizzle pos = c ^ ((row>>1)&3). fp32 out.
template<int BM, int BN>
__global__ __launch_bounds__(256) void gemm_bt_kernel(
    const unsigned short* __restrict__ A,
    const unsigned short* __restrict__ Bt,
    const float* __restrict__ bias,
    float* __restrict__ out,
    int M, int N, int K) {
  constexpr int MT = BM / 32, NT = BN / 32;
  constexpr int RPWA = BM / 4, RPWB = BN / 4;
  constexpr int NJA = RPWA / 16, NJB = RPWB / 16;
  __shared__ unsigned short As[2][BM * 32];
  __shared__ unsigned short Bs[2][BN * 32];
  const int t = threadIdx.x;
  const int wave = t >> 6, lane = t & 63;
  const int L = lane & 15, quad = lane >> 4;
  const int wm = (wave >> 1) * (BM / 2), wn = (wave & 1) * (BN / 2);
  const int m0 = blockIdx.y * BM, n0 = blockIdx.x * BN;

  const int drow = lane >> 2;
  const int dch  = (lane & 3) ^ ((drow >> 1) & 3);
  const int foff = ((quad ^ ((L >> 1) & 3)) * 8);

  const unsigned short* Ab = A  + (size_t)(m0 + wave * RPWA + drow) * K + dch * 8;
  const unsigned short* Bb = Bt + (size_t)(n0 + wave * RPWB + drow) * K + dch * 8;

  f32x4 acc[MT][NT] = {};
  const int NK = K >> 5;

  #pragma unroll
  for (int j = 0; j < NJA; ++j)
    load_lds16(Ab + (size_t)j * 16 * K, &As[0][(wave * RPWA + j * 16) * 32]);
  #pragma unroll
  for (int j = 0; j < NJB; ++j)
    load_lds16(Bb + (size_t)j * 16 * K, &Bs[0][(wave * RPWB + j * 16) * 32]);

  int buf = 0;
  for (int kt = 0; kt < NK; ++kt) {
    asm volatile("" ::: "memory");
    __builtin_amdgcn_s_waitcnt(0x0F70);
    __builtin_amdgcn_s_barrier();
    asm volatile("" ::: "memory");

    if (kt + 1 < NK) {
      #pragma unroll
      for (int j = 0; j < NJA; ++j)
        load_lds16(Ab + (size_t)j * 16 * K + (kt + 1) * 32,
                   &As[buf ^ 1][(wave * RPWA + j * 16) * 32]);
      #pragma unroll
      for (int j = 0; j < NJB; ++j)
        load_lds16(Bb + (size_t)j * 16 * K + (kt + 1) * 32,
                   &Bs[buf ^ 1][(wave * RPWB + j * 16) * 32]);
    }

    bf16x8 af[MT], bf[NT];
    #pragma unroll
    for (int mt = 0; mt < MT; ++mt)
      af[mt] = *reinterpret_cast<const bf16x8*>(&As[buf][(wm + mt * 16 + L) * 32 + foff]);
    #pragma unroll
    for (int nt = 0; nt < NT; ++nt)
      bf[nt] = *reinterpret_cast<const bf16x8*>(&Bs[buf][(wn + nt * 16 + L) * 32 + foff]);
    __builtin_amdgcn_s_setprio(1);
    #pragma unroll
    for (int mt = 0; mt < MT; ++mt)
      #pragma unroll
      for (int nt = 0; nt < NT; ++nt)
        acc[mt][nt] = __builtin_amdgcn_mfma_f32_16x16x32_bf16(af[mt], bf[nt], acc[mt][nt], 0, 0, 0);
    __builtin_amdgcn_s_setprio(0);
    buf ^= 1;
  }

  #pragma unroll
  for (int mt = 0; mt < MT; ++mt)
    #pragma unroll
    for (int nt = 0; nt < NT; ++nt) {
      int col = n0 + wn + nt * 16 + L;
      float b = bias[col];
      #pragma unroll
      for (int r = 0; r < 4; ++r) {
        int row = m0 + wm + mt * 16 + quad * 4 + r;
        out[(size_t)row * N + col] = acc[mt][nt][r] + b;
      }
    }
}

// ---------- flash attention v5 (round-1/3 best-measured config) ----------
// Softmax VALU diet: HW v_cvt_pk_bf16_f32, raw v_exp_f32, setprio around MFMA.
// Pair fold-balance + XCD-aware decode: all 16 pair-blocks of a bh share one mod-8
// residue class -> same XCD L2 caches that bh's K/V (cuts HBM re-fetch ~8x).
// S^T via swapped MFMA operands; 3-buffer K/V pipeline, single barrier per tile.
__global__ __launch_bounds__(256) void attn_kernel(
    const unsigned short* __restrict__ qkv,
    const unsigned short* __restrict__ vt,
    unsigned short* __restrict__ y) {
  __shared__ unsigned short Ks[3][64 * 64];  // [key][d], swizzled chunks
  __shared__ unsigned short Vs[3][64 * 64];  // [d][key], swizzled chunks
  __shared__ unsigned short Ps[4][32][72];   // per-wave P[qrow][key]: rows 0-15 A, 16-31 B

  const int t = threadIdx.x;
  const int wave = t >> 6, lane = t & 63;
  const int L = lane & 15, quad = lane >> 4;
  // XCD-aware decode: residue class (b&7) -> XCD; 4 bh per class x 16 pairs
  const int b = blockIdx.x;
  const int bh = (b & 7) * 4 + ((b >> 3) & 3);
  const int pi = b >> 5;                // pair index 0..15
  const int tA = pi, tB = 31 - pi;      // 64-row q-tile indices
  const int rowA0 = tA * 64 + wave * 16;
  const int rowB0 = tB * 64 + wave * 16;
  const int ntiles = tB + 1;

  const unsigned short* qb  = qkv + ((size_t)bh * 2048) * 64;
  const unsigned short* kb  = qkv + ((size_t)(32 + bh) * 2048) * 64;
  const unsigned short* vtb = vt + (size_t)bh * 64 * 2048;

  // DMA per-lane constants: 8 rows (128B each) per instruction
  const int drow = lane >> 3;           // 0..7
  const int dch  = (lane & 7) ^ drow;   // source chunk (xor swizzle)
  // frag-read swizzle offsets: chunk c of row r stored at c^(r&7)
  const int fo0 = ((quad ^ (L & 7)) * 8);
  const int fo1 = (((quad + 4) ^ (L & 7)) * 8);

  // Q fragments (A/B-operand layout, direct from global, resident all kernel)
  bf16x8 qfA[2], qfB[2];
  #pragma unroll
  for (int h = 0; h < 2; ++h) {
    qfA[h] = *reinterpret_cast<const bf16x8*>(qb + (size_t)(rowA0 + L) * 64 + h * 32 + quad * 8);
    qfB[h] = *reinterpret_cast<const bf16x8*>(qb + (size_t)(rowB0 + L) * 64 + h * 32 + quad * 8);
  }

  f32x4 oA[4] = {}, oB[4] = {};
  float rsA = 0.f, rsB = 0.f;

  // prologue: stage tile 0 -> buf 0 (4 DMA instrs per wave per stage)
  {
    #pragma unroll
    for (int j = 0; j < 2; ++j) {
      int r0 = wave * 16 + j * 8;
      load_lds16(kb  + (size_t)(0 + r0 + drow) * 64 + dch * 8, &Ks[0][r0 * 64]);
      load_lds16(vtb + (size_t)(r0 + drow) * 2048 + 0 + dch * 8, &Vs[0][r0 * 64]);
    }
  }

  int buf = 0;
  for (int kt = 0; kt < ntiles; ++kt) {
    // stage kt+1 (clamped dummy on last iter keeps vmcnt accounting uniform)
    const int nkt = (kt + 1 < ntiles) ? kt + 1 : ntiles - 1;
    const int nbuf = (buf == 2) ? 0 : buf + 1;
    {
      const int kg = nkt * 64;
      #pragma unroll
      for (int j = 0; j < 2; ++j) {
        int r0 = wave * 16 + j * 8;
        load_lds16(kb  + (size_t)(kg + r0 + drow) * 64 + dch * 8, &Ks[nbuf][r0 * 64]);
        load_lds16(vtb + (size_t)(r0 + drow) * 2048 + kg + dch * 8, &Vs[nbuf][r0 * 64]);
      }
    }
    asm volatile("" ::: "memory");
    __builtin_amdgcn_s_waitcnt(0x0F74);   // vmcnt(4): tile kt's 4 DMAs done; kt+1 in flight
    __builtin_amdgcn_s_barrier();
    asm volatile("" ::: "memory");

    const bool actA = (kt <= tA);

    // ---- S^T = K Q^T : D[m=key][n=qrow] (A=K-frag, B=Q-frag) ----
    bf16x8 kf[4][2];
    #pragma unroll
    for (int nt = 0; nt < 4; ++nt) {
      kf[nt][0] = *reinterpret_cast<const bf16x8*>(&Ks[buf][(nt * 16 + L) * 64 + fo0]);
      kf[nt][1] = *reinterpret_cast<const bf16x8*>(&Ks[buf][(nt * 16 + L) * 64 + fo1]);
    }

    f32x4 sB[4] = {};
    __builtin_amdgcn_s_setprio(1);
    #pragma unroll
    for (int nt = 0; nt < 4; ++nt) {
      sB[nt] = __builtin_amdgcn_mfma_f32_16x16x32_bf16(kf[nt][0], qfB[0], sB[nt], 0, 0, 0);
      sB[nt] = __builtin_amdgcn_mfma_f32_16x16x32_bf16(kf[nt][1], qfB[1], sB[nt], 0, 0, 0);
    }
    __builtin_amdgcn_s_setprio(0);
    if (kt == tB) {  // diagonal mask: key > qrow -> -inf
      #pragma unroll
      for (int nt = 0; nt < 4; ++nt) {
        int key0 = kt * 64 + nt * 16 + quad * 4;
        int qr = rowB0 + L;
        #pragma unroll
        for (int r = 0; r < 4; ++r)
          if (key0 + r > qr) sB[nt][r] = -3.0e38f;
      }
    }
    #pragma unroll
    for (int nt = 0; nt < 4; ++nt) {
      float p0 = exp2_fast(sB[nt][0]), p1 = exp2_fast(sB[nt][1]);
      float p2 = exp2_fast(sB[nt][2]), p3 = exp2_fast(sB[nt][3]);
      rsB += (p0 + p1) + (p2 + p3);
      uint2 pk;
      pk.x = pkbf(p0, p1);
      pk.y = pkbf(p2, p3);
      *reinterpret_cast<uint2*>(&Ps[wave][16 + L][nt * 16 + quad * 4]) = pk;
    }

    if (actA) {
      f32x4 sA[4] = {};
      __builtin_amdgcn_s_setprio(1);
      #pragma unroll
      for (int nt = 0; nt < 4; ++nt) {
        sA[nt] = __builtin_amdgcn_mfma_f32_16x16x32_bf16(kf[nt][0], qfA[0], sA[nt], 0, 0, 0);
        sA[nt] = __builtin_amdgcn_mfma_f32_16x16x32_bf16(kf[nt][1], qfA[1], sA[nt], 0, 0, 0);
      }
      __builtin_amdgcn_s_setprio(0);
      if (kt == tA) {
        #pragma unroll
        for (int nt = 0; nt < 4; ++nt) {
          int key0 = kt * 64 + nt * 16 + quad * 4;
          int qr = rowA0 + L;
          #pragma unroll
          for (int r = 0; r < 4; ++r)
            if (key0 + r > qr) sA[nt][r] = -3.0e38f;
        }
      }
      #pragma unroll
      for (int nt = 0; nt < 4; ++nt) {
        float p0 = exp2_fast(sA[nt][0]), p1 = exp2_fast(sA[nt][1]);
        float p2 = exp2_fast(sA[nt][2]), p3 = exp2_fast(sA[nt][3]);
        rsA += (p0 + p1) + (p2 + p3);
        uint2 pk;
        pk.x = pkbf(p0, p1);
        pk.y = pkbf(p2, p3);
        *reinterpret_cast<uint2*>(&Ps[wave][L][nt * 16 + quad * 4]) = pk;
      }
    }

    // ---- O += P V ----  (P in A-layout directly from Ps[qrow][key])
    bf16x8 vf[4][2];
    #pragma unroll
    for (int nt = 0; nt < 4; ++nt) {
      vf[nt][0] = *reinterpret_cast<const bf16x8*>(&Vs[buf][(nt * 16 + L) * 64 + fo0]);
      vf[nt][1] = *reinterpret_cast<const bf16x8*>(&Vs[buf][(nt * 16 + L) * 64 + fo1]);
    }
    bf16x8 pb0 = *reinterpret_cast<const bf16x8*>(&Ps[wave][16 + L][quad * 8]);
    bf16x8 pb1 = *reinterpret_cast<const bf16x8*>(&Ps[wave][16 + L][32 + quad * 8]);
    __builtin_amdgcn_s_setprio(1);
    #pragma unroll
    for (int nt = 0; nt < 4; ++nt) {
      oB[nt] = __builtin_amdgcn_mfma_f32_16x16x32_bf16(pb0, vf[nt][0], oB[nt], 0, 0, 0);
      oB[nt] = __builtin_amdgcn_mfma_f32_16x16x32_bf16(pb1, vf[nt][1], oB[nt], 0, 0, 0);
    }
    __builtin_amdgcn_s_setprio(0);
    if (actA) {
      bf16x8 pa0 = *reinterpret_cast<const bf16x8*>(&Ps[wave][L][quad * 8]);
      bf16x8 pa1 = *reinterpret_cast<const bf16x8*>(&Ps[wave][L][32 + quad * 8]);
      __builtin_amdgcn_s_setprio(1);
      #pragma unroll
      for (int nt = 0; nt < 4; ++nt) {
        oA[nt] = __builtin_amdgcn_mfma_f32_16x16x32_bf16(pa0, vf[nt][0], oA[nt], 0, 0, 0);
        oA[nt] = __builtin_amdgcn_mfma_f32_16x16x32_bf16(pa1, vf[nt][1], oA[nt], 0, 0, 0);
      }
      __builtin_amdgcn_s_setprio(0);
    }
    buf = nbuf;
  }

  // ---- epilogue: reduce l across quads (rows live on L), fetch per-output-row via shfl ----
  float a = rsA; a += __shfl_xor(a, 16, 64); a += __shfl_xor(a, 32, 64);
  float b2 = rsB; b2 += __shfl_xor(b2, 16, 64); b2 += __shfl_xor(b2, 32, 64);
  float invA[4], invB[4];
  #pragma unroll
  for (int r = 0; r < 4; ++r) {
    invA[r] = 1.0f / __shfl(a, quad * 4 + r, 64);
    invB[r] = 1.0f / __shfl(b2, quad * 4 + r, 64);
  }
  const int bb = bh >> 4, hh = bh & 15;
  #pragma unroll
  for (int nt = 0; nt < 4; ++nt)
    #pragma unroll
    for (int r = 0; r < 4; ++r) {
      int rA = rowA0 + quad * 4 + r;
      int rB = rowB0 + quad * 4 + r;
      int col = hh * 64 + nt * 16 + L;
      y[((size_t)bb * 2048 + rA) * 1024 + col] = f2bf(oA[nt][r] * invA[r]);
      y[((size_t)bb * 2048 + rB) * 1024 + col] = f2bf(oB[nt][r] * invB[r]);
    }
  // drain outstanding dummy DMAs before LDS dealloc at wave end
  __builtin_amdgcn_s_waitcnt(0);
}

extern "C" void kernel_launch(void* const* d_in, const int* in_sizes, int n_in,
                              void* d_out, int out_size, void* d_ws, size_t ws_size,
                              hipStream_t stream) {
  const float* x      = (const float*)d_in[0];  // [2,2048,1024]
  const float* w_attn = (const float*)d_in[1];  // [1024,3072]
  const float* b_attn = (const float*)d_in[2];  // [3072]
  const float* w_proj = (const float*)d_in[3];  // [1024,1024]
  const float* b_proj = (const float*)d_in[4];  // [1024]
  float* out = (float*)d_out;                   // [2,2048,1024] fp32

  unsigned short* ws = (unsigned short*)d_ws;
  unsigned short* xb     = ws;                    //  4194304 [4096,1024]
  unsigned short* wattnT = xb + 4194304;          //  3145728 [3072,1024]
  unsigned short* wprojT = wattnT + 3145728;      //  1048576 [1024,1024]
  unsigned short* qkv    = wprojT + 1048576;      // 12582912 [3][32][2048][64] (v unused)
  unsigned short* yb     = qkv + 12582912;        //  4194304 [4096,1024]
  unsigned short* vt     = yb + 4194304;          //  4194304 [32][64][2048]

  // fused prep: cast x + transpose both weight matrices (one launch)
  prep_kernel<<<8192, 256, 0, stream>>>(x, w_attn, w_proj, xb, wattnT, wprojT);

  // QKV: 256x192 tiles -> grid 16x16 = exactly 1 block/CU, phase-split schedule
  gemm_qkv_kernel<<<dim3(16, 16), 512, 0, stream>>>(xb, wattnT, b_attn, qkv, vt);
  // attention (fold-balanced, XCD-grouped, 3-buffer pipelined)
  attn_kernel<<<dim3(512), 256, 0, stream>>>(qkv, vt, yb);
  // proj: M=4096, N=1024, K=1024; 64^2 tiles (round-3 config)
  gemm_bt_kernel<64, 64><<<dim3(16, 64), 256, 0, stream>>>(yb, wprojT, b_proj, out, 4096, 1024, 1024);
}

// Round 9
// 190.749 us; speedup vs baseline: 1.0996x; 1.0090x over previous
//
#include <hip/hip_runtime.h>
#include <stdint.h>

// B=2, T=2048, C=1024, H=16, HD=64
// qkv ws layout: [3][B*H=32][T=2048][HD=64] bf16 (v region unused); vt: [32][64][2048] bf16

typedef short bf16x8 __attribute__((ext_vector_type(8)));
typedef float f32x4 __attribute__((ext_vector_type(4)));

__device__ inline unsigned short f2bf(float f) {
  union { float f; uint32_t u; } v; v.f = f;
  uint32_t u = v.u;
  u += 0x7FFFu + ((u >> 16) & 1u);   // round-to-nearest-even
  return (unsigned short)(u >> 16);
}

// pack two fp32 -> two bf16 in one dword — HW instruction (no builtin on gfx950, m240)
__device__ inline unsigned pkbf(float a, float b) {
  unsigned r;
  asm("v_cvt_pk_bf16_f32 %0, %1, %2" : "=v"(r) : "v"(a), "v"(b));
  return r;
}

// raw v_exp_f32 (2^x) without OCML range fixup; inputs bounded, -3e38 -> +0
__device__ inline float exp2_fast(float x) {
#if __has_builtin(__builtin_amdgcn_exp2f)
  return __builtin_amdgcn_exp2f(x);
#else
  float r; asm("v_exp_f32 %0, %1" : "=v"(r) : "v"(x)); return r;
#endif
}

// async global->LDS, 16B per lane, dest = lds base + lane*16
__device__ inline void load_lds16(const unsigned short* g, unsigned short* l) {
  __builtin_amdgcn_global_load_lds(
      (const __attribute__((address_space(1))) unsigned int*)(const void*)g,
      (__attribute__((address_space(3))) unsigned int*)(void*)l, 16, 0, 0);
}

// ---------- fused prep: cast x -> bf16, transpose+cast w_attn, w_proj ----------
// blocks [0,4096): cast 1048576 float4 of x
// blocks [4096,7168): transpose w_attn [1024][3072] -> [3072][1024]
// blocks [7168,8192): transpose w_proj [1024][1024] -> [1024][1024]
__global__ __launch_bounds__(256) void prep_kernel(
    const float* __restrict__ x, const float* __restrict__ w_attn,
    const float* __restrict__ w_proj,
    unsigned short* __restrict__ xb, unsigned short* __restrict__ wattnT,
    unsigned short* __restrict__ wprojT) {
  __shared__ float tile[32][33];
  const int b = blockIdx.x, t = threadIdx.x;
  if (b < 4096) {
    int i = b * 256 + t;                      // < 1048576 always
    float4 f = reinterpret_cast<const float4*>(x)[i];
    ushort4 o;
    o.x = f2bf(f.x); o.y = f2bf(f.y); o.z = f2bf(f.z); o.w = f2bf(f.w);
    reinterpret_cast<ushort4*>(xb)[i] = o;
    return;
  }
  const float* in; unsigned short* out; int R, Cn, bx, by;
  if (b < 7168) {
    int bb = b - 4096;
    in = w_attn; out = wattnT; R = 1024; Cn = 3072;
    bx = (bb % 96) * 32; by = (bb / 96) * 32;
  } else {
    int bb = b - 7168;
    in = w_proj; out = wprojT; R = 1024; Cn = 1024;
    bx = (bb % 32) * 32; by = (bb / 32) * 32;
  }
  const int tx = t & 31, ty = t >> 5;         // block acts as (32,8)
  #pragma unroll
  for (int i = 0; i < 32; i += 8)
    tile[ty + i][tx] = in[(size_t)(by + ty + i) * Cn + bx + tx];
  __syncthreads();
  #pragma unroll
  for (int i = 0; i < 32; i += 8)
    out[(size_t)(bx + ty + i) * R + by + tx] = f2bf(tile[tx][ty + i]);
}

// ---------- QKV GEMM: 128x96 tile -> 4 independent 4-wave chains per CU ----------
// m97's config cell: same 2-phase schedule as round-3 (2 LDS buffers, ONE barrier
// per K-step, vmcnt(0); stage kt+1 AFTER the barrier into buf^1), but grid
// 32x32 = 1024 blocks = EXACTLY 4 blocks/CU, and regs ~100 (acc[4][3] = 48 AGPR)
// so RF fits all 4. Four independent barrier-groups interleave their stalls
// (round 5's 2x8-wave blocks could not: convoys stall at block granularity).
// LDS 28 KB. B tile 96 rows = 6 staging instrs, unevenly split (w0:2 w1:2 w2:1
// w3:1) — fine under per-wave vmcnt(0) + barrier.
// Unpadded tiles, chunk swizzle pos = c ^ ((row>>1)&3).
// Epilogue: QKV scatter q/k -> qkv layout (q scaled by 0.125*log2e), v -> vt[bh][d][t].
__global__ __launch_bounds__(256) void gemm_qkv_kernel(
    const unsigned short* __restrict__ A,
    const unsigned short* __restrict__ Bt,
    const float* __restrict__ bias,
    unsigned short* __restrict__ qkv,
    unsigned short* __restrict__ vtp) {
  constexpr int K = 1024;
  __shared__ unsigned short As[2][128 * 32];   // 16 KB
  __shared__ unsigned short Bs[2][96 * 32];    // 12 KB
  const int t = threadIdx.x;
  const int wave = t >> 6, lane = t & 63;
  const int L = lane & 15, quad = lane >> 4;
  const int wm = (wave >> 1) * 64, wn = (wave & 1) * 48;
  const int m0 = blockIdx.y * 128, n0 = blockIdx.x * 96;

  // DMA per-lane source mapping: 16 rows per instr, lane>>2 = row, lane&3 = stored pos
  const int drow = lane >> 2;
  const int dch  = (lane & 3) ^ ((drow >> 1) & 3);
  // frag read: logical chunk `quad` of row L stored at quad ^ ((L>>1)&3)
  const int foff = ((quad ^ ((L >> 1) & 3)) * 8);

  const unsigned short* Ab  = A  + (size_t)(m0 + wave * 32 + drow) * K + dch * 8;
  const unsigned short* Bb  = Bt + (size_t)(n0 + wave * 16 + drow) * K + dch * 8;
  // extra B rows 64-95 staged by waves 0,1
  const unsigned short* Bb2 = Bt + (size_t)(n0 + 64 + wave * 16 + drow) * K + dch * 8;

  f32x4 acc[4][3] = {};

  // prologue: stage tile 0 -> buf 0
  #pragma unroll
  for (int j = 0; j < 2; ++j)
    load_lds16(Ab + (size_t)j * 16 * K, &As[0][(wave * 32 + j * 16) * 32]);
  load_lds16(Bb, &Bs[0][(wave * 16) * 32]);
  if (wave < 2) load_lds16(Bb2, &Bs[0][(64 + wave * 16) * 32]);

  int buf = 0;
  for (int kt = 0; kt < 32; ++kt) {
    asm volatile("" ::: "memory");
    __builtin_amdgcn_s_waitcnt(0x0F70);   // vmcnt(0): own DMAs for tile kt landed
    __builtin_amdgcn_s_barrier();         // everyone's DMAs landed; buf^1 consumed
    asm volatile("" ::: "memory");

    if (kt + 1 < 32) {                    // stage kt+1 into the other buffer
      const int ko = (kt + 1) * 32;
      #pragma unroll
      for (int j = 0; j < 2; ++j)
        load_lds16(Ab + (size_t)j * 16 * K + ko, &As[buf ^ 1][(wave * 32 + j * 16) * 32]);
      load_lds16(Bb + ko, &Bs[buf ^ 1][(wave * 16) * 32]);
      if (wave < 2) load_lds16(Bb2 + ko, &Bs[buf ^ 1][(64 + wave * 16) * 32]);
    }

    bf16x8 af[4], bf[3];
    #pragma unroll
    for (int mt = 0; mt < 4; ++mt)
      af[mt] = *reinterpret_cast<const bf16x8*>(&As[buf][(wm + mt * 16 + L) * 32 + foff]);
    #pragma unroll
    for (int nt = 0; nt < 3; ++nt)
      bf[nt] = *reinterpret_cast<const bf16x8*>(&Bs[buf][(wn + nt * 16 + L) * 32 + foff]);
    __builtin_amdgcn_s_setprio(1);
    #pragma unroll
    for (int mt = 0; mt < 4; ++mt)
      #pragma unroll
      for (int nt = 0; nt < 3; ++nt)
        acc[mt][nt] = __builtin_amdgcn_mfma_f32_16x16x32_bf16(af[mt], bf[nt], acc[mt][nt], 0, 0, 0);
    __builtin_amdgcn_s_setprio(0);
    buf ^= 1;
  }

  // epilogue: QKV scatter (q scaled by 0.125*log2e folded in; v -> vt transpose)
  #pragma unroll
  for (int mt = 0; mt < 4; ++mt)
    #pragma unroll
    for (int nt = 0; nt < 3; ++nt) {
      int col = n0 + wn + nt * 16 + L;          // 0..3071
      int sel = col >> 10, cc = col & 1023;
      int h = cc >> 6, d = cc & 63;
      float b = bias[col];
      float sc = (sel == 0) ? 0.18033688011112042f : 1.0f;
      #pragma unroll
      for (int r = 0; r < 4; ++r) {
        int row = m0 + wm + mt * 16 + quad * 4 + r;  // 0..4095
        int bb = row >> 11, tt = row & 2047;
        float val = (acc[mt][nt][r] + b) * sc;
        if (sel == 2) {
          vtp[((size_t)(bb * 16 + h) * 64 + d) * 2048 + tt] = f2bf(val);
        } else {
          qkv[(((size_t)sel * 32 + (size_t)(bb * 16 + h)) * 2048 + tt) * 64 + d] = f2bf(val);
        }
      }
    }
}

// ---------- bf16 MFMA GEMM, BK=32 (proj; round-3 proven config) ----------
// 2 LDS buffers, ONE barrier per K-step, vmcnt(0). Unpadded BMx32-short tiles,
// chunk swizzle pos = c ^ ((row>>1)&3). fp32 out.
template<int BM, int BN>
__global__ __launch_bounds__(256) void gemm_bt_kernel(
    const unsigned short* __restrict__ A,
    const unsigned short* __restrict__ Bt,
    const float* __restrict__ bias,
    float* __restrict__ out,
    int M, int N, int K) {
  constexpr int MT = BM / 32, NT = BN / 32;
  constexpr int RPWA = BM / 4, RPWB = BN / 4;
  constexpr int NJA = RPWA / 16, NJB = RPWB / 16;
  __shared__ unsigned short As[2][BM * 32];
  __shared__ unsigned short Bs[2][BN * 32];
  const int t = threadIdx.x;
  const int wave = t >> 6, lane = t & 63;
  const int L = lane & 15, quad = lane >> 4;
  const int wm = (wave >> 1) * (BM / 2), wn = (wave & 1) * (BN / 2);
  const int m0 = blockIdx.y * BM, n0 = blockIdx.x * BN;

  const int drow = lane >> 2;
  const int dch  = (lane & 3) ^ ((drow >> 1) & 3);
  const int foff = ((quad ^ ((L >> 1) & 3)) * 8);

  const unsigned short* Ab = A  + (size_t)(m0 + wave * RPWA + drow) * K + dch * 8;
  const unsigned short* Bb = Bt + (size_t)(n0 + wave * RPWB + drow) * K + dch * 8;

  f32x4 acc[MT][NT] = {};
  const int NK = K >> 5;

  #pragma unroll
  for (int j = 0; j < NJA; ++j)
    load_lds16(Ab + (size_t)j * 16 * K, &As[0][(wave * RPWA + j * 16) * 32]);
  #pragma unroll
  for (int j = 0; j < NJB; ++j)
    load_lds16(Bb + (size_t)j * 16 * K, &Bs[0][(wave * RPWB + j * 16) * 32]);

  int buf = 0;
  for (int kt = 0; kt < NK; ++kt) {
    asm volatile("" ::: "memory");
    __builtin_amdgcn_s_waitcnt(0x0F70);
    __builtin_amdgcn_s_barrier();
    asm volatile("" ::: "memory");

    if (kt + 1 < NK) {
      #pragma unroll
      for (int j = 0; j < NJA; ++j)
        load_lds16(Ab + (size_t)j * 16 * K + (kt + 1) * 32,
                   &As[buf ^ 1][(wave * RPWA + j * 16) * 32]);
      #pragma unroll
      for (int j = 0; j < NJB; ++j)
        load_lds16(Bb + (size_t)j * 16 * K + (kt + 1) * 32,
                   &Bs[buf ^ 1][(wave * RPWB + j * 16) * 32]);
    }

    bf16x8 af[MT], bf[NT];
    #pragma unroll
    for (int mt = 0; mt < MT; ++mt)
      af[mt] = *reinterpret_cast<const bf16x8*>(&As[buf][(wm + mt * 16 + L) * 32 + foff]);
    #pragma unroll
    for (int nt = 0; nt < NT; ++nt)
      bf[nt] = *reinterpret_cast<const bf16x8*>(&Bs[buf][(wn + nt * 16 + L) * 32 + foff]);
    __builtin_amdgcn_s_setprio(1);
    #pragma unroll
    for (int mt = 0; mt < MT; ++mt)
      #pragma unroll
      for (int nt = 0; nt < NT; ++nt)
        acc[mt][nt] = __builtin_amdgcn_mfma_f32_16x16x32_bf16(af[mt], bf[nt], acc[mt][nt], 0, 0, 0);
    __builtin_amdgcn_s_setprio(0);
    buf ^= 1;
  }

  #pragma unroll
  for (int mt = 0; mt < MT; ++mt)
    #pragma unroll
    for (int nt = 0; nt < NT; ++nt) {
      int col = n0 + wn + nt * 16 + L;
      float b = bias[col];
      #pragma unroll
      for (int r = 0; r < 4; ++r) {
        int row = m0 + wm + mt * 16 + quad * 4 + r;
        out[(size_t)row * N + col] = acc[mt][nt][r] + b;
      }
    }
}

// ---------- flash attention v5 (round-1/3 best-measured config) ----------
// Softmax VALU diet: HW v_cvt_pk_bf16_f32, raw v_exp_f32, setprio around MFMA.
// Pair fold-balance + XCD-aware decode: all 16 pair-blocks of a bh share one mod-8
// residue class -> same XCD L2 caches that bh's K/V (cuts HBM re-fetch ~8x).
// S^T via swapped MFMA operands; 3-buffer K/V pipeline, single barrier per tile.
__global__ __launch_bounds__(256) void attn_kernel(
    const unsigned short* __restrict__ qkv,
    const unsigned short* __restrict__ vt,
    unsigned short* __restrict__ y) {
  __shared__ unsigned short Ks[3][64 * 64];  // [key][d], swizzled chunks
  __shared__ unsigned short Vs[3][64 * 64];  // [d][key], swizzled chunks
  __shared__ unsigned short Ps[4][32][72];   // per-wave P[qrow][key]: rows 0-15 A, 16-31 B

  const int t = threadIdx.x;
  const int wave = t >> 6, lane = t & 63;
  const int L = lane & 15, quad = lane >> 4;
  // XCD-aware decode: residue class (b&7) -> XCD; 4 bh per class x 16 pairs
  const int b = blockIdx.x;
  const int bh = (b & 7) * 4 + ((b >> 3) & 3);
  const int pi = b >> 5;                // pair index 0..15
  const int tA = pi, tB = 31 - pi;      // 64-row q-tile indices
  const int rowA0 = tA * 64 + wave * 16;
  const int rowB0 = tB * 64 + wave * 16;
  const int ntiles = tB + 1;

  const unsigned short* qb  = qkv + ((size_t)bh * 2048) * 64;
  const unsigned short* kb  = qkv + ((size_t)(32 + bh) * 2048) * 64;
  const unsigned short* vtb = vt + (size_t)bh * 64 * 2048;

  // DMA per-lane constants: 8 rows (128B each) per instruction
  const int drow = lane >> 3;           // 0..7
  const int dch  = (lane & 7) ^ drow;   // source chunk (xor swizzle)
  // frag-read swizzle offsets: chunk c of row r stored at c^(r&7)
  const int fo0 = ((quad ^ (L & 7)) * 8);
  const int fo1 = (((quad + 4) ^ (L & 7)) * 8);

  // Q fragments (A/B-operand layout, direct from global, resident all kernel)
  bf16x8 qfA[2], qfB[2];
  #pragma unroll
  for (int h = 0; h < 2; ++h) {
    qfA[h] = *reinterpret_cast<const bf16x8*>(qb + (size_t)(rowA0 + L) * 64 + h * 32 + quad * 8);
    qfB[h] = *reinterpret_cast<const bf16x8*>(qb + (size_t)(rowB0 + L) * 64 + h * 32 + quad * 8);
  }

  f32x4 oA[4] = {}, oB[4] = {};
  float rsA = 0.f, rsB = 0.f;

  // prologue: stage tile 0 -> buf 0 (4 DMA instrs per wave per stage)
  {
    #pragma unroll
    for (int j = 0; j < 2; ++j) {
      int r0 = wave * 16 + j * 8;
      load_lds16(kb  + (size_t)(0 + r0 + drow) * 64 + dch * 8, &Ks[0][r0 * 64]);
      load_lds16(vtb + (size_t)(r0 + drow) * 2048 + 0 + dch * 8, &Vs[0][r0 * 64]);
    }
  }

  int buf = 0;
  for (int kt = 0; kt < ntiles; ++kt) {
    // stage kt+1 (clamped dummy on last iter keeps vmcnt accounting uniform)
    const int nkt = (kt + 1 < ntiles) ? kt + 1 : ntiles - 1;
    const int nbuf = (buf == 2) ? 0 : buf + 1;
    {
      const int kg = nkt * 64;
      #pragma unroll
      for (int j = 0; j < 2; ++j) {
        int r0 = wave * 16 + j * 8;
        load_lds16(kb  + (size_t)(kg + r0 + drow) * 64 + dch * 8, &Ks[nbuf][r0 * 64]);
        load_lds16(vtb + (size_t)(r0 + drow) * 2048 + kg + dch * 8, &Vs[nbuf][r0 * 64]);
      }
    }
    asm volatile("" ::: "memory");
    __builtin_amdgcn_s_waitcnt(0x0F74);   // vmcnt(4): tile kt's 4 DMAs done; kt+1 in flight
    __builtin_amdgcn_s_barrier();
    asm volatile("" ::: "memory");

    const bool actA = (kt <= tA);

    // ---- S^T = K Q^T : D[m=key][n=qrow] (A=K-frag, B=Q-frag) ----
    bf16x8 kf[4][2];
    #pragma unroll
    for (int nt = 0; nt < 4; ++nt) {
      kf[nt][0] = *reinterpret_cast<const bf16x8*>(&Ks[buf][(nt * 16 + L) * 64 + fo0]);
      kf[nt][1] = *reinterpret_cast<const bf16x8*>(&Ks[buf][(nt * 16 + L) * 64 + fo1]);
    }

    f32x4 sB[4] = {};
    __builtin_amdgcn_s_setprio(1);
    #pragma unroll
    for (int nt = 0; nt < 4; ++nt) {
      sB[nt] = __builtin_amdgcn_mfma_f32_16x16x32_bf16(kf[nt][0], qfB[0], sB[nt], 0, 0, 0);
      sB[nt] = __builtin_amdgcn_mfma_f32_16x16x32_bf16(kf[nt][1], qfB[1], sB[nt], 0, 0, 0);
    }
    __builtin_amdgcn_s_setprio(0);
    if (kt == tB) {  // diagonal mask: key > qrow -> -inf
      #pragma unroll
      for (int nt = 0; nt < 4; ++nt) {
        int key0 = kt * 64 + nt * 16 + quad * 4;
        int qr = rowB0 + L;
        #pragma unroll
        for (int r = 0; r < 4; ++r)
          if (key0 + r > qr) sB[nt][r] = -3.0e38f;
      }
    }
    #pragma unroll
    for (int nt = 0; nt < 4; ++nt) {
      float p0 = exp2_fast(sB[nt][0]), p1 = exp2_fast(sB[nt][1]);
      float p2 = exp2_fast(sB[nt][2]), p3 = exp2_fast(sB[nt][3]);
      rsB += (p0 + p1) + (p2 + p3);
      uint2 pk;
      pk.x = pkbf(p0, p1);
      pk.y = pkbf(p2, p3);
      *reinterpret_cast<uint2*>(&Ps[wave][16 + L][nt * 16 + quad * 4]) = pk;
    }

    if (actA) {
      f32x4 sA[4] = {};
      __builtin_amdgcn_s_setprio(1);
      #pragma unroll
      for (int nt = 0; nt < 4; ++nt) {
        sA[nt] = __builtin_amdgcn_mfma_f32_16x16x32_bf16(kf[nt][0], qfA[0], sA[nt], 0, 0, 0);
        sA[nt] = __builtin_amdgcn_mfma_f32_16x16x32_bf16(kf[nt][1], qfA[1], sA[nt], 0, 0, 0);
      }
      __builtin_amdgcn_s_setprio(0);
      if (kt == tA) {
        #pragma unroll
        for (int nt = 0; nt < 4; ++nt) {
          int key0 = kt * 64 + nt * 16 + quad * 4;
          int qr = rowA0 + L;
          #pragma unroll
          for (int r = 0; r < 4; ++r)
            if (key0 + r > qr) sA[nt][r] = -3.0e38f;
        }
      }
      #pragma unroll
      for (int nt = 0; nt < 4; ++nt) {
        float p0 = exp2_fast(sA[nt][0]), p1 = exp2_fast(sA[nt][1]);
        float p2 = exp2_fast(sA[nt][2]), p3 = exp2_fast(sA[nt][3]);
        rsA += (p0 + p1) + (p2 + p3);
        uint2 pk;
        pk.x = pkbf(p0, p1);
        pk.y = pkbf(p2, p3);
        *reinterpret_cast<uint2*>(&Ps[wave][L][nt * 16 + quad * 4]) = pk;
      }
    }

    // ---- O += P V ----  (P in A-layout directly from Ps[qrow][key])
    bf16x8 vf[4][2];
    #pragma unroll
    for (int nt = 0; nt < 4; ++nt) {
      vf[nt][0] = *reinterpret_cast<const bf16x8*>(&Vs[buf][(nt * 16 + L) * 64 + fo0]);
      vf[nt][1] = *reinterpret_cast<const bf16x8*>(&Vs[buf][(nt * 16 + L) * 64 + fo1]);
    }
    bf16x8 pb0 = *reinterpret_cast<const bf16x8*>(&Ps[wave][16 + L][quad * 8]);
    bf16x8 pb1 = *reinterpret_cast<const bf16x8*>(&Ps[wave][16 + L][32 + quad * 8]);
    __builtin_amdgcn_s_setprio(1);
    #pragma unroll
    for (int nt = 0; nt < 4; ++nt) {
      oB[nt] = __builtin_amdgcn_mfma_f32_16x16x32_bf16(pb0, vf[nt][0], oB[nt], 0, 0, 0);
      oB[nt] = __builtin_amdgcn_mfma_f32_16x16x32_bf16(pb1, vf[nt][1], oB[nt], 0, 0, 0);
    }
    __builtin_amdgcn_s_setprio(0);
    if (actA) {
      bf16x8 pa0 = *reinterpret_cast<const bf16x8*>(&Ps[wave][L][quad * 8]);
      bf16x8 pa1 = *reinterpret_cast<const bf16x8*>(&Ps[wave][L][32 + quad * 8]);
      __builtin_amdgcn_s_setprio(1);
      #pragma unroll
      for (int nt = 0; nt < 4; ++nt) {
        oA[nt] = __builtin_amdgcn_mfma_f32_16x16x32_bf16(pa0, vf[nt][0], oA[nt], 0, 0, 0);
        oA[nt] = __builtin_amdgcn_mfma_f32_16x16x32_bf16(pa1, vf[nt][1], oA[nt], 0, 0, 0);
      }
      __builtin_amdgcn_s_setprio(0);
    }
    buf = nbuf;
  }

  // ---- epilogue: reduce l across quads (rows live on L), fetch per-output-row via shfl ----
  float a = rsA; a += __shfl_xor(a, 16, 64); a += __shfl_xor(a, 32, 64);
  float b2 = rsB; b2 += __shfl_xor(b2, 16, 64); b2 += __shfl_xor(b2, 32, 64);
  float invA[4], invB[4];
  #pragma unroll
  for (int r = 0; r < 4; ++r) {
    invA[r] = 1.0f / __shfl(a, quad * 4 + r, 64);
    invB[r] = 1.0f / __shfl(b2, quad * 4 + r, 64);
  }
  const int bb = bh >> 4, hh = bh & 15;
  #pragma unroll
  for (int nt = 0; nt < 4; ++nt)
    #pragma unroll
    for (int r = 0; r < 4; ++r) {
      int rA = rowA0 + quad * 4 + r;
      int rB = rowB0 + quad * 4 + r;
      int col = hh * 64 + nt * 16 + L;
      y[((size_t)bb * 2048 + rA) * 1024 + col] = f2bf(oA[nt][r] * invA[r]);
      y[((size_t)bb * 2048 + rB) * 1024 + col] = f2bf(oB[nt][r] * invB[r]);
    }
  // drain outstanding dummy DMAs before LDS dealloc at wave end
  __builtin_amdgcn_s_waitcnt(0);
}

extern "C" void kernel_launch(void* const* d_in, const int* in_sizes, int n_in,
                              void* d_out, int out_size, void* d_ws, size_t ws_size,
                              hipStream_t stream) {
  const float* x      = (const float*)d_in[0];  // [2,2048,1024]
  const float* w_attn = (const float*)d_in[1];  // [1024,3072]
  const float* b_attn = (const float*)d_in[2];  // [3072]
  const float* w_proj = (const float*)d_in[3];  // [1024,1024]
  const float* b_proj = (const float*)d_in[4];  // [1024]
  float* out = (float*)d_out;                   // [2,2048,1024] fp32

  unsigned short* ws = (unsigned short*)d_ws;
  unsigned short* xb     = ws;                    //  4194304 [4096,1024]
  unsigned short* wattnT = xb + 4194304;          //  3145728 [3072,1024]
  unsigned short* wprojT = wattnT + 3145728;      //  1048576 [1024,1024]
  unsigned short* qkv    = wprojT + 1048576;      // 12582912 [3][32][2048][64] (v unused)
  unsigned short* yb     = qkv + 12582912;        //  4194304 [4096,1024]
  unsigned short* vt     = yb + 4194304;          //  4194304 [32][64][2048]

  // fused prep: cast x + transpose both weight matrices (one launch)
  prep_kernel<<<8192, 256, 0, stream>>>(x, w_attn, w_proj, xb, wattnT, wprojT);

  // QKV: M=4096, N=3072, K=1024; 128x96 tiles -> grid 32x32 = 1024 blocks
  //  = exactly 4 independent 4-wave chains per CU (m97's config cell)
  gemm_qkv_kernel<<<dim3(32, 32), 256, 0, stream>>>(xb, wattnT, b_attn, qkv, vt);
  // attention (fold-balanced, XCD-grouped, 3-buffer pipelined)
  attn_kernel<<<dim3(512), 256, 0, stream>>>(qkv, vt, yb);
  // proj: M=4096, N=1024, K=1024; 64^2 tiles (round-3 config, 4 chains/CU)
  gemm_bt_kernel<64, 64><<<dim3(16, 64), 256, 0, stream>>>(yb, wprojT, b_proj, out, 4096, 1024, 1024);
}

// Round 10
// 187.793 us; speedup vs baseline: 1.1169x; 1.0157x over previous
//
#include <hip/hip_runtime.h>
#include <stdint.h>

// B=2, T=2048, C=1024, H=16, HD=64
// qkv ws layout: [3][B*H=32][T=2048][HD=64] bf16 (v region unused); vt: [32][64][2048] bf16

typedef short bf16x8 __attribute__((ext_vector_type(8)));
typedef float f32x4 __attribute__((ext_vector_type(4)));

__device__ inline unsigned short f2bf(float f) {
  union { float f; uint32_t u; } v; v.f = f;
  uint32_t u = v.u;
  u += 0x7FFFu + ((u >> 16) & 1u);   // round-to-nearest-even
  return (unsigned short)(u >> 16);
}

// pack two fp32 -> two bf16 in one dword — HW instruction (no builtin on gfx950, m240)
__device__ inline unsigned pkbf(float a, float b) {
  unsigned r;
  asm("v_cvt_pk_bf16_f32 %0, %1, %2" : "=v"(r) : "v"(a), "v"(b));
  return r;
}

// raw v_exp_f32 (2^x) without OCML range fixup; inputs bounded, -3e38 -> +0
__device__ inline float exp2_fast(float x) {
#if __has_builtin(__builtin_amdgcn_exp2f)
  return __builtin_amdgcn_exp2f(x);
#else
  float r; asm("v_exp_f32 %0, %1" : "=v"(r) : "v"(x)); return r;
#endif
}

// async global->LDS, 16B per lane, dest = lds base + lane*16
__device__ inline void load_lds16(const unsigned short* g, unsigned short* l) {
  __builtin_amdgcn_global_load_lds(
      (const __attribute__((address_space(1))) unsigned int*)(const void*)g,
      (__attribute__((address_space(3))) unsigned int*)(void*)l, 16, 0, 0);
}

// ---------- fused prep: cast x -> bf16, transpose+cast w_attn, w_proj ----------
// blocks [0,4096): cast 1048576 float4 of x
// blocks [4096,7168): transpose w_attn [1024][3072] -> [3072][1024]
// blocks [7168,8192): transpose w_proj [1024][1024] -> [1024][1024]
__global__ __launch_bounds__(256) void prep_kernel(
    const float* __restrict__ x, const float* __restrict__ w_attn,
    const float* __restrict__ w_proj,
    unsigned short* __restrict__ xb, unsigned short* __restrict__ wattnT,
    unsigned short* __restrict__ wprojT) {
  __shared__ float tile[32][33];
  const int b = blockIdx.x, t = threadIdx.x;
  if (b < 4096) {
    int i = b * 256 + t;                      // < 1048576 always
    float4 f = reinterpret_cast<const float4*>(x)[i];
    ushort4 o;
    o.x = f2bf(f.x); o.y = f2bf(f.y); o.z = f2bf(f.z); o.w = f2bf(f.w);
    reinterpret_cast<ushort4*>(xb)[i] = o;
    return;
  }
  const float* in; unsigned short* out; int R, Cn, bx, by;
  if (b < 7168) {
    int bb = b - 4096;
    in = w_attn; out = wattnT; R = 1024; Cn = 3072;
    bx = (bb % 96) * 32; by = (bb / 96) * 32;
  } else {
    int bb = b - 7168;
    in = w_proj; out = wprojT; R = 1024; Cn = 1024;
    bx = (bb % 32) * 32; by = (bb / 32) * 32;
  }
  const int tx = t & 31, ty = t >> 5;         // block acts as (32,8)
  #pragma unroll
  for (int i = 0; i < 32; i += 8)
    tile[ty + i][tx] = in[(size_t)(by + ty + i) * Cn + bx + tx];
  __syncthreads();
  #pragma unroll
  for (int i = 0; i < 32; i += 8)
    out[(size_t)(bx + ty + i) * R + by + tx] = f2bf(tile[tx][ty + i]);
}

// ---------- bf16 MFMA GEMM: C[M,N] = A[M,K] * Bt[N,K]^T + bias ----------
// Round-3 proven config (best measured: QKV 45.5us at 128^2, 768 blocks) PLUS
// XCD-rect block decode (the ONLY change this round): xcd = bid&7 (HW
// round-robin); each XCD owns a contiguous rw x rh rectangle of the block grid,
// cutting its private-L2 working set from ~15MB to ~3-5MB (FETCH 36MB -> ~22MB
// predicted). Decode-only: schedule, resources, launch bounds untouched.
// Schedule: 2 LDS buffers, ONE barrier per K-step, vmcnt(0):
//   iter kt: vmcnt(0) [own tile-kt DMAs done]; barrier [all waves' DMAs done AND
//   buf^1's old tile consumed by everyone]; stage(kt+1 -> buf^1); compute(kt).
// Unpadded BMx32-short tiles, chunk swizzle pos = c ^ ((row>>1)&3).
// mode 0: write fp32 to out [M,N]
// mode 1: QKV scatter: q/k -> qkv layout (q scaled by 0.125*log2e), v -> vt[bh][d][t]
template<int BM, int BN>
__global__ __launch_bounds__(256) void gemm_bt_kernel(
    const unsigned short* __restrict__ A,
    const unsigned short* __restrict__ Bt,
    const float* __restrict__ bias,
    void* __restrict__ outp,
    unsigned short* __restrict__ vtp,
    int M, int N, int K, int rw, int mode) {
  constexpr int MT = BM / 32, NT = BN / 32;   // frags per wave per dim
  constexpr int RPWA = BM / 4, RPWB = BN / 4; // staged rows per wave
  constexpr int NJA = RPWA / 16, NJB = RPWB / 16;
  __shared__ unsigned short As[2][BM * 32];
  __shared__ unsigned short Bs[2][BN * 32];
  const int t = threadIdx.x;
  const int wave = t >> 6, lane = t & 63;
  const int L = lane & 15, quad = lane >> 4;
  const int wm = (wave >> 1) * (BM / 2), wn = (wave & 1) * (BN / 2);

  // XCD-rect decode: 8 XCDs tile the (N/BN x M/BM) block grid as 2 wide x 4 tall
  // rectangles of rw x rh blocks (rh = blocks_per_xcd / rw).
  const int xcd = blockIdx.x & 7, idx = blockIdx.x >> 3;
  const int rh = (int)(gridDim.x >> 3) / rw;
  const int bx = (xcd & 1) * rw + idx % rw;
  const int by = (xcd >> 1) * rh + idx / rw;
  const int m0 = by * BM, n0 = bx * BN;

  // DMA per-lane source mapping: 16 rows per instr, lane>>2 = row, lane&3 = stored pos
  const int drow = lane >> 2;
  const int dch  = (lane & 3) ^ ((drow >> 1) & 3);
  // frag read: logical chunk `quad` of row L stored at quad ^ ((L>>1)&3)
  const int foff = ((quad ^ ((L >> 1) & 3)) * 8);

  const unsigned short* Ab = A  + (size_t)(m0 + wave * RPWA + drow) * K + dch * 8;
  const unsigned short* Bb = Bt + (size_t)(n0 + wave * RPWB + drow) * K + dch * 8;

  f32x4 acc[MT][NT] = {};
  const int NK = K >> 5;

  // prologue: stage tile 0 -> buf 0
  #pragma unroll
  for (int j = 0; j < NJA; ++j)
    load_lds16(Ab + (size_t)j * 16 * K, &As[0][(wave * RPWA + j * 16) * 32]);
  #pragma unroll
  for (int j = 0; j < NJB; ++j)
    load_lds16(Bb + (size_t)j * 16 * K, &Bs[0][(wave * RPWB + j * 16) * 32]);

  int buf = 0;
  for (int kt = 0; kt < NK; ++kt) {
    asm volatile("" ::: "memory");
    __builtin_amdgcn_s_waitcnt(0x0F70);   // vmcnt(0): own DMAs for tile kt landed
    __builtin_amdgcn_s_barrier();         // everyone's DMAs landed; buf^1 consumed
    asm volatile("" ::: "memory");

    if (kt + 1 < NK) {                    // stage kt+1 into the other buffer
      #pragma unroll
      for (int j = 0; j < NJA; ++j)
        load_lds16(Ab + (size_t)j * 16 * K + (kt + 1) * 32,
                   &As[buf ^ 1][(wave * RPWA + j * 16) * 32]);
      #pragma unroll
      for (int j = 0; j < NJB; ++j)
        load_lds16(Bb + (size_t)j * 16 * K + (kt + 1) * 32,
                   &Bs[buf ^ 1][(wave * RPWB + j * 16) * 32]);
    }

    bf16x8 af[MT], bf[NT];
    #pragma unroll
    for (int mt = 0; mt < MT; ++mt)
      af[mt] = *reinterpret_cast<const bf16x8*>(&As[buf][(wm + mt * 16 + L) * 32 + foff]);
    #pragma unroll
    for (int nt = 0; nt < NT; ++nt)
      bf[nt] = *reinterpret_cast<const bf16x8*>(&Bs[buf][(wn + nt * 16 + L) * 32 + foff]);
    __builtin_amdgcn_s_setprio(1);
    #pragma unroll
    for (int mt = 0; mt < MT; ++mt)
      #pragma unroll
      for (int nt = 0; nt < NT; ++nt)
        acc[mt][nt] = __builtin_amdgcn_mfma_f32_16x16x32_bf16(af[mt], bf[nt], acc[mt][nt], 0, 0, 0);
    __builtin_amdgcn_s_setprio(0);
    buf ^= 1;
  }

  if (mode == 0) {
    float* out = (float*)outp;
    #pragma unroll
    for (int mt = 0; mt < MT; ++mt)
      #pragma unroll
      for (int nt = 0; nt < NT; ++nt) {
        int col = n0 + wn + nt * 16 + L;
        float b = bias[col];
        #pragma unroll
        for (int r = 0; r < 4; ++r) {
          int row = m0 + wm + mt * 16 + quad * 4 + r;
          out[(size_t)row * N + col] = acc[mt][nt][r] + b;
        }
      }
  } else {
    unsigned short* qkv = (unsigned short*)outp;  // [3][32][2048][64]
    #pragma unroll
    for (int mt = 0; mt < MT; ++mt)
      #pragma unroll
      for (int nt = 0; nt < NT; ++nt) {
        int col = n0 + wn + nt * 16 + L;          // 0..3071
        int sel = col >> 10, cc = col & 1023;
        int h = cc >> 6, d = cc & 63;
        float b = bias[col];
        // fold 1/sqrt(64) * log2(e) into q so attention uses exp2 directly
        float sc = (sel == 0) ? 0.18033688011112042f : 1.0f;
        #pragma unroll
        for (int r = 0; r < 4; ++r) {
          int row = m0 + wm + mt * 16 + quad * 4 + r;  // 0..4095
          int bb = row >> 11, tt = row & 2047;
          float val = (acc[mt][nt][r] + b) * sc;
          if (sel == 2) {
            // v -> vt[bh][d][t]  (fused V transpose)
            vtp[((size_t)(bb * 16 + h) * 64 + d) * 2048 + tt] = f2bf(val);
          } else {
            qkv[(((size_t)sel * 32 + (size_t)(bb * 16 + h)) * 2048 + tt) * 64 + d] = f2bf(val);
          }
        }
      }
  }
}

// ---------- flash attention v5 (round-1/3 best-measured config) ----------
// Softmax VALU diet: HW v_cvt_pk_bf16_f32, raw v_exp_f32, setprio around MFMA.
// Pair fold-balance + XCD-aware decode: all 16 pair-blocks of a bh share one mod-8
// residue class -> same XCD L2 caches that bh's K/V (cuts HBM re-fetch ~8x).
// S^T via swapped MFMA operands; 3-buffer K/V pipeline, single barrier per tile.
__global__ __launch_bounds__(256) void attn_kernel(
    const unsigned short* __restrict__ qkv,
    const unsigned short* __restrict__ vt,
    unsigned short* __restrict__ y) {
  __shared__ unsigned short Ks[3][64 * 64];  // [key][d], swizzled chunks
  __shared__ unsigned short Vs[3][64 * 64];  // [d][key], swizzled chunks
  __shared__ unsigned short Ps[4][32][72];   // per-wave P[qrow][key]: rows 0-15 A, 16-31 B

  const int t = threadIdx.x;
  const int wave = t >> 6, lane = t & 63;
  const int L = lane & 15, quad = lane >> 4;
  // XCD-aware decode: residue class (b&7) -> XCD; 4 bh per class x 16 pairs
  const int b = blockIdx.x;
  const int bh = (b & 7) * 4 + ((b >> 3) & 3);
  const int pi = b >> 5;                // pair index 0..15
  const int tA = pi, tB = 31 - pi;      // 64-row q-tile indices
  const int rowA0 = tA * 64 + wave * 16;
  const int rowB0 = tB * 64 + wave * 16;
  const int ntiles = tB + 1;

  const unsigned short* qb  = qkv + ((size_t)bh * 2048) * 64;
  const unsigned short* kb  = qkv + ((size_t)(32 + bh) * 2048) * 64;
  const unsigned short* vtb = vt + (size_t)bh * 64 * 2048;

  // DMA per-lane constants: 8 rows (128B each) per instruction
  const int drow = lane >> 3;           // 0..7
  const int dch  = (lane & 7) ^ drow;   // source chunk (xor swizzle)
  // frag-read swizzle offsets: chunk c of row r stored at c^(r&7)
  const int fo0 = ((quad ^ (L & 7)) * 8);
  const int fo1 = (((quad + 4) ^ (L & 7)) * 8);

  // Q fragments (A/B-operand layout, direct from global, resident all kernel)
  bf16x8 qfA[2], qfB[2];
  #pragma unroll
  for (int h = 0; h < 2; ++h) {
    qfA[h] = *reinterpret_cast<const bf16x8*>(qb + (size_t)(rowA0 + L) * 64 + h * 32 + quad * 8);
    qfB[h] = *reinterpret_cast<const bf16x8*>(qb + (size_t)(rowB0 + L) * 64 + h * 32 + quad * 8);
  }

  f32x4 oA[4] = {}, oB[4] = {};
  float rsA = 0.f, rsB = 0.f;

  // prologue: stage tile 0 -> buf 0 (4 DMA instrs per wave per stage)
  {
    #pragma unroll
    for (int j = 0; j < 2; ++j) {
      int r0 = wave * 16 + j * 8;
      load_lds16(kb  + (size_t)(0 + r0 + drow) * 64 + dch * 8, &Ks[0][r0 * 64]);
      load_lds16(vtb + (size_t)(r0 + drow) * 2048 + 0 + dch * 8, &Vs[0][r0 * 64]);
    }
  }

  int buf = 0;
  for (int kt = 0; kt < ntiles; ++kt) {
    // stage kt+1 (clamped dummy on last iter keeps vmcnt accounting uniform)
    const int nkt = (kt + 1 < ntiles) ? kt + 1 : ntiles - 1;
    const int nbuf = (buf == 2) ? 0 : buf + 1;
    {
      const int kg = nkt * 64;
      #pragma unroll
      for (int j = 0; j < 2; ++j) {
        int r0 = wave * 16 + j * 8;
        load_lds16(kb  + (size_t)(kg + r0 + drow) * 64 + dch * 8, &Ks[nbuf][r0 * 64]);
        load_lds16(vtb + (size_t)(r0 + drow) * 2048 + kg + dch * 8, &Vs[nbuf][r0 * 64]);
      }
    }
    asm volatile("" ::: "memory");
    __builtin_amdgcn_s_waitcnt(0x0F74);   // vmcnt(4): tile kt's 4 DMAs done; kt+1 in flight
    __builtin_amdgcn_s_barrier();
    asm volatile("" ::: "memory");

    const bool actA = (kt <= tA);

    // ---- S^T = K Q^T : D[m=key][n=qrow] (A=K-frag, B=Q-frag) ----
    bf16x8 kf[4][2];
    #pragma unroll
    for (int nt = 0; nt < 4; ++nt) {
      kf[nt][0] = *reinterpret_cast<const bf16x8*>(&Ks[buf][(nt * 16 + L) * 64 + fo0]);
      kf[nt][1] = *reinterpret_cast<const bf16x8*>(&Ks[buf][(nt * 16 + L) * 64 + fo1]);
    }

    f32x4 sB[4] = {};
    __builtin_amdgcn_s_setprio(1);
    #pragma unroll
    for (int nt = 0; nt < 4; ++nt) {
      sB[nt] = __builtin_amdgcn_mfma_f32_16x16x32_bf16(kf[nt][0], qfB[0], sB[nt], 0, 0, 0);
      sB[nt] = __builtin_amdgcn_mfma_f32_16x16x32_bf16(kf[nt][1], qfB[1], sB[nt], 0, 0, 0);
    }
    __builtin_amdgcn_s_setprio(0);
    if (kt == tB) {  // diagonal mask: key > qrow -> -inf
      #pragma unroll
      for (int nt = 0; nt < 4; ++nt) {
        int key0 = kt * 64 + nt * 16 + quad * 4;
        int qr = rowB0 + L;
        #pragma unroll
        for (int r = 0; r < 4; ++r)
          if (key0 + r > qr) sB[nt][r] = -3.0e38f;
      }
    }
    #pragma unroll
    for (int nt = 0; nt < 4; ++nt) {
      float p0 = exp2_fast(sB[nt][0]), p1 = exp2_fast(sB[nt][1]);
      float p2 = exp2_fast(sB[nt][2]), p3 = exp2_fast(sB[nt][3]);
      rsB += (p0 + p1) + (p2 + p3);
      uint2 pk;
      pk.x = pkbf(p0, p1);
      pk.y = pkbf(p2, p3);
      *reinterpret_cast<uint2*>(&Ps[wave][16 + L][nt * 16 + quad * 4]) = pk;
    }

    if (actA) {
      f32x4 sA[4] = {};
      __builtin_amdgcn_s_setprio(1);
      #pragma unroll
      for (int nt = 0; nt < 4; ++nt) {
        sA[nt] = __builtin_amdgcn_mfma_f32_16x16x32_bf16(kf[nt][0], qfA[0], sA[nt], 0, 0, 0);
        sA[nt] = __builtin_amdgcn_mfma_f32_16x16x32_bf16(kf[nt][1], qfA[1], sA[nt], 0, 0, 0);
      }
      __builtin_amdgcn_s_setprio(0);
      if (kt == tA) {
        #pragma unroll
        for (int nt = 0; nt < 4; ++nt) {
          int key0 = kt * 64 + nt * 16 + quad * 4;
          int qr = rowA0 + L;
          #pragma unroll
          for (int r = 0; r < 4; ++r)
            if (key0 + r > qr) sA[nt][r] = -3.0e38f;
        }
      }
      #pragma unroll
      for (int nt = 0; nt < 4; ++nt) {
        float p0 = exp2_fast(sA[nt][0]), p1 = exp2_fast(sA[nt][1]);
        float p2 = exp2_fast(sA[nt][2]), p3 = exp2_fast(sA[nt][3]);
        rsA += (p0 + p1) + (p2 + p3);
        uint2 pk;
        pk.x = pkbf(p0, p1);
        pk.y = pkbf(p2, p3);
        *reinterpret_cast<uint2*>(&Ps[wave][L][nt * 16 + quad * 4]) = pk;
      }
    }

    // ---- O += P V ----  (P in A-layout directly from Ps[qrow][key])
    bf16x8 vf[4][2];
    #pragma unroll
    for (int nt = 0; nt < 4; ++nt) {
      vf[nt][0] = *reinterpret_cast<const bf16x8*>(&Vs[buf][(nt * 16 + L) * 64 + fo0]);
      vf[nt][1] = *reinterpret_cast<const bf16x8*>(&Vs[buf][(nt * 16 + L) * 64 + fo1]);
    }
    bf16x8 pb0 = *reinterpret_cast<const bf16x8*>(&Ps[wave][16 + L][quad * 8]);
    bf16x8 pb1 = *reinterpret_cast<const bf16x8*>(&Ps[wave][16 + L][32 + quad * 8]);
    __builtin_amdgcn_s_setprio(1);
    #pragma unroll
    for (int nt = 0; nt < 4; ++nt) {
      oB[nt] = __builtin_amdgcn_mfma_f32_16x16x32_bf16(pb0, vf[nt][0], oB[nt], 0, 0, 0);
      oB[nt] = __builtin_amdgcn_mfma_f32_16x16x32_bf16(pb1, vf[nt][1], oB[nt], 0, 0, 0);
    }
    __builtin_amdgcn_s_setprio(0);
    if (actA) {
      bf16x8 pa0 = *reinterpret_cast<const bf16x8*>(&Ps[wave][L][quad * 8]);
      bf16x8 pa1 = *reinterpret_cast<const bf16x8*>(&Ps[wave][L][32 + quad * 8]);
      __builtin_amdgcn_s_setprio(1);
      #pragma unroll
      for (int nt = 0; nt < 4; ++nt) {
        oA[nt] = __builtin_amdgcn_mfma_f32_16x16x32_bf16(pa0, vf[nt][0], oA[nt], 0, 0, 0);
        oA[nt] = __builtin_amdgcn_mfma_f32_16x16x32_bf16(pa1, vf[nt][1], oA[nt], 0, 0, 0);
      }
      __builtin_amdgcn_s_setprio(0);
    }
    buf = nbuf;
  }

  // ---- epilogue: reduce l across quads (rows live on L), fetch per-output-row via shfl ----
  float a = rsA; a += __shfl_xor(a, 16, 64); a += __shfl_xor(a, 32, 64);
  float b2 = rsB; b2 += __shfl_xor(b2, 16, 64); b2 += __shfl_xor(b2, 32, 64);
  float invA[4], invB[4];
  #pragma unroll
  for (int r = 0; r < 4; ++r) {
    invA[r] = 1.0f / __shfl(a, quad * 4 + r, 64);
    invB[r] = 1.0f / __shfl(b2, quad * 4 + r, 64);
  }
  const int bb = bh >> 4, hh = bh & 15;
  #pragma unroll
  for (int nt = 0; nt < 4; ++nt)
    #pragma unroll
    for (int r = 0; r < 4; ++r) {
      int rA = rowA0 + quad * 4 + r;
      int rB = rowB0 + quad * 4 + r;
      int col = hh * 64 + nt * 16 + L;
      y[((size_t)bb * 2048 + rA) * 1024 + col] = f2bf(oA[nt][r] * invA[r]);
      y[((size_t)bb * 2048 + rB) * 1024 + col] = f2bf(oB[nt][r] * invB[r]);
    }
  // drain outstanding dummy DMAs before LDS dealloc at wave end
  __builtin_amdgcn_s_waitcnt(0);
}

extern "C" void kernel_launch(void* const* d_in, const int* in_sizes, int n_in,
                              void* d_out, int out_size, void* d_ws, size_t ws_size,
                              hipStream_t stream) {
  const float* x      = (const float*)d_in[0];  // [2,2048,1024]
  const float* w_attn = (const float*)d_in[1];  // [1024,3072]
  const float* b_attn = (const float*)d_in[2];  // [3072]
  const float* w_proj = (const float*)d_in[3];  // [1024,1024]
  const float* b_proj = (const float*)d_in[4];  // [1024]
  float* out = (float*)d_out;                   // [2,2048,1024] fp32

  unsigned short* ws = (unsigned short*)d_ws;
  unsigned short* xb     = ws;                    //  4194304 [4096,1024]
  unsigned short* wattnT = xb + 4194304;          //  3145728 [3072,1024]
  unsigned short* wprojT = wattnT + 3145728;      //  1048576 [1024,1024]
  unsigned short* qkv    = wprojT + 1048576;      // 12582912 [3][32][2048][64] (v unused)
  unsigned short* yb     = qkv + 12582912;        //  4194304 [4096,1024]
  unsigned short* vt     = yb + 4194304;          //  4194304 [32][64][2048]

  // fused prep: cast x + transpose both weight matrices (one launch)
  prep_kernel<<<8192, 256, 0, stream>>>(x, w_attn, w_proj, xb, wattnT, wprojT);

  // QKV: M=4096, N=3072, K=1024; 128^2 tiles, 768 blocks (3 chains/CU — round-3
  // best) + XCD-rect decode: 8 XCDs as 2x4 rects of 12x8 blocks (rw=12)
  gemm_bt_kernel<128, 128><<<dim3(768), 256, 0, stream>>>(xb, wattnT, b_attn, qkv, vt, 4096, 3072, 1024, 12, 1);
  // attention (fold-balanced, XCD-grouped, 3-buffer pipelined)
  attn_kernel<<<dim3(512), 256, 0, stream>>>(qkv, vt, yb);
  // proj: M=4096, N=1024, K=1024; 64^2 tiles, 1024 blocks + XCD-rect (rw=8 -> 8x16 rects)
  gemm_bt_kernel<64, 64><<<dim3(1024), 256, 0, stream>>>(yb, wprojT, b_proj, out, nullptr, 4096, 1024, 1024, 8, 0);
}

// Round 11
// 177.716 us; speedup vs baseline: 1.1802x; 1.0567x over previous
//
#include <hip/hip_runtime.h>
#include <stdint.h>

// B=2, T=2048, C=1024, H=16, HD=64
// qkv ws layout: [3][B*H=32][T=2048][HD=64] bf16 (v region unused); vt: [32][64][2048] bf16

typedef short bf16x8 __attribute__((ext_vector_type(8)));
typedef float f32x4 __attribute__((ext_vector_type(4)));

__device__ inline unsigned short f2bf(float f) {
  union { float f; uint32_t u; } v; v.f = f;
  uint32_t u = v.u;
  u += 0x7FFFu + ((u >> 16) & 1u);   // round-to-nearest-even
  return (unsigned short)(u >> 16);
}

// pack two fp32 -> two bf16 in one dword — HW instruction (no builtin on gfx950, m240)
__device__ inline unsigned pkbf(float a, float b) {
  unsigned r;
  asm("v_cvt_pk_bf16_f32 %0, %1, %2" : "=v"(r) : "v"(a), "v"(b));
  return r;
}

// raw v_exp_f32 (2^x) without OCML range fixup; inputs bounded, -3e38 -> +0
__device__ inline float exp2_fast(float x) {
#if __has_builtin(__builtin_amdgcn_exp2f)
  return __builtin_amdgcn_exp2f(x);
#else
  float r; asm("v_exp_f32 %0, %1" : "=v"(r) : "v"(x)); return r;
#endif
}

// async global->LDS, 16B per lane, dest = lds base + lane*16
__device__ inline void load_lds16(const unsigned short* g, unsigned short* l) {
  __builtin_amdgcn_global_load_lds(
      (const __attribute__((address_space(1))) unsigned int*)(const void*)g,
      (__attribute__((address_space(3))) unsigned int*)(void*)l, 16, 0, 0);
}

// ---------- fused prep: cast x -> bf16, transpose+cast w_attn, w_proj ----------
// One launch instead of three (isolated effect ~-2.5us, r3<->r6 decomposition).
// blocks [0,4096): cast 1048576 float4 of x
// blocks [4096,7168): transpose w_attn [1024][3072] -> [3072][1024]
// blocks [7168,8192): transpose w_proj [1024][1024] -> [1024][1024]
__global__ __launch_bounds__(256) void prep_kernel(
    const float* __restrict__ x, const float* __restrict__ w_attn,
    const float* __restrict__ w_proj,
    unsigned short* __restrict__ xb, unsigned short* __restrict__ wattnT,
    unsigned short* __restrict__ wprojT) {
  __shared__ float tile[32][33];
  const int b = blockIdx.x, t = threadIdx.x;
  if (b < 4096) {
    int i = b * 256 + t;                      // < 1048576 always
    float4 f = reinterpret_cast<const float4*>(x)[i];
    ushort4 o;
    o.x = f2bf(f.x); o.y = f2bf(f.y); o.z = f2bf(f.z); o.w = f2bf(f.w);
    reinterpret_cast<ushort4*>(xb)[i] = o;
    return;
  }
  const float* in; unsigned short* out; int R, Cn, bx, by;
  if (b < 7168) {
    int bb = b - 4096;
    in = w_attn; out = wattnT; R = 1024; Cn = 3072;
    bx = (bb % 96) * 32; by = (bb / 96) * 32;
  } else {
    int bb = b - 7168;
    in = w_proj; out = wprojT; R = 1024; Cn = 1024;
    bx = (bb % 32) * 32; by = (bb / 32) * 32;
  }
  const int tx = t & 31, ty = t >> 5;         // block acts as (32,8)
  #pragma unroll
  for (int i = 0; i < 32; i += 8)
    tile[ty + i][tx] = in[(size_t)(by + ty + i) * Cn + bx + tx];
  __syncthreads();
  #pragma unroll
  for (int i = 0; i < 32; i += 8)
    out[(size_t)(bx + ty + i) * R + by + tx] = f2bf(tile[tx][ty + i]);
}

// ---------- bf16 MFMA GEMM: C[M,N] = A[M,K] * Bt[N,K]^T + bias ----------
// ROUND-3 PROVEN OPTIMUM of the 2-phase family (QKV 45.5us; 10 rounds of
// variants all >= this). LINEAR block decode is load-bearing: co-resident
// blocks bid,bid+1,bid+2 share the same A-panel (L2-hot) — the r10 XCD-rect
// decode cut chip FETCH 43% but broke the sharing and regressed 15%.
// Schedule: 2 LDS buffers, ONE barrier per K-step, vmcnt(0):
//   iter kt: vmcnt(0) [own tile-kt DMAs done]; barrier [all waves' DMAs done AND
//   buf^1's old tile consumed by everyone]; stage(kt+1 -> buf^1); compute(kt).
// Unpadded BMx32-short tiles, chunk swizzle pos = c ^ ((row>>1)&3).
// mode 0: write fp32 to out [M,N]
// mode 1: QKV scatter: q/k -> qkv layout (q scaled by 0.125*log2e), v -> vt[bh][d][t]
template<int BM, int BN>
__global__ __launch_bounds__(256) void gemm_bt_kernel(
    const unsigned short* __restrict__ A,
    const unsigned short* __restrict__ Bt,
    const float* __restrict__ bias,
    void* __restrict__ outp,
    unsigned short* __restrict__ vtp,
    int M, int N, int K, int mode) {
  constexpr int MT = BM / 32, NT = BN / 32;   // frags per wave per dim
  constexpr int RPWA = BM / 4, RPWB = BN / 4; // staged rows per wave
  constexpr int NJA = RPWA / 16, NJB = RPWB / 16;
  __shared__ unsigned short As[2][BM * 32];
  __shared__ unsigned short Bs[2][BN * 32];
  const int t = threadIdx.x;
  const int wave = t >> 6, lane = t & 63;
  const int L = lane & 15, quad = lane >> 4;
  const int wm = (wave >> 1) * (BM / 2), wn = (wave & 1) * (BN / 2);
  const int m0 = blockIdx.y * BM, n0 = blockIdx.x * BN;

  // DMA per-lane source mapping: 16 rows per instr, lane>>2 = row, lane&3 = stored pos
  const int drow = lane >> 2;
  const int dch  = (lane & 3) ^ ((drow >> 1) & 3);
  // frag read: logical chunk `quad` of row L stored at quad ^ ((L>>1)&3)
  const int foff = ((quad ^ ((L >> 1) & 3)) * 8);

  const unsigned short* Ab = A  + (size_t)(m0 + wave * RPWA + drow) * K + dch * 8;
  const unsigned short* Bb = Bt + (size_t)(n0 + wave * RPWB + drow) * K + dch * 8;

  f32x4 acc[MT][NT] = {};
  const int NK = K >> 5;

  // prologue: stage tile 0 -> buf 0
  #pragma unroll
  for (int j = 0; j < NJA; ++j)
    load_lds16(Ab + (size_t)j * 16 * K, &As[0][(wave * RPWA + j * 16) * 32]);
  #pragma unroll
  for (int j = 0; j < NJB; ++j)
    load_lds16(Bb + (size_t)j * 16 * K, &Bs[0][(wave * RPWB + j * 16) * 32]);

  int buf = 0;
  for (int kt = 0; kt < NK; ++kt) {
    asm volatile("" ::: "memory");
    __builtin_amdgcn_s_waitcnt(0x0F70);   // vmcnt(0): own DMAs for tile kt landed
    __builtin_amdgcn_s_barrier();         // everyone's DMAs landed; buf^1 consumed
    asm volatile("" ::: "memory");

    if (kt + 1 < NK) {                    // stage kt+1 into the other buffer
      #pragma unroll
      for (int j = 0; j < NJA; ++j)
        load_lds16(Ab + (size_t)j * 16 * K + (kt + 1) * 32,
                   &As[buf ^ 1][(wave * RPWA + j * 16) * 32]);
      #pragma unroll
      for (int j = 0; j < NJB; ++j)
        load_lds16(Bb + (size_t)j * 16 * K + (kt + 1) * 32,
                   &Bs[buf ^ 1][(wave * RPWB + j * 16) * 32]);
    }

    bf16x8 af[MT], bf[NT];
    #pragma unroll
    for (int mt = 0; mt < MT; ++mt)
      af[mt] = *reinterpret_cast<const bf16x8*>(&As[buf][(wm + mt * 16 + L) * 32 + foff]);
    #pragma unroll
    for (int nt = 0; nt < NT; ++nt)
      bf[nt] = *reinterpret_cast<const bf16x8*>(&Bs[buf][(wn + nt * 16 + L) * 32 + foff]);
    __builtin_amdgcn_s_setprio(1);
    #pragma unroll
    for (int mt = 0; mt < MT; ++mt)
      #pragma unroll
      for (int nt = 0; nt < NT; ++nt)
        acc[mt][nt] = __builtin_amdgcn_mfma_f32_16x16x32_bf16(af[mt], bf[nt], acc[mt][nt], 0, 0, 0);
    __builtin_amdgcn_s_setprio(0);
    buf ^= 1;
  }

  if (mode == 0) {
    float* out = (float*)outp;
    #pragma unroll
    for (int mt = 0; mt < MT; ++mt)
      #pragma unroll
      for (int nt = 0; nt < NT; ++nt) {
        int col = n0 + wn + nt * 16 + L;
        float b = bias[col];
        #pragma unroll
        for (int r = 0; r < 4; ++r) {
          int row = m0 + wm + mt * 16 + quad * 4 + r;
          out[(size_t)row * N + col] = acc[mt][nt][r] + b;
        }
      }
  } else {
    unsigned short* qkv = (unsigned short*)outp;  // [3][32][2048][64]
    #pragma unroll
    for (int mt = 0; mt < MT; ++mt)
      #pragma unroll
      for (int nt = 0; nt < NT; ++nt) {
        int col = n0 + wn + nt * 16 + L;          // 0..3071
        int sel = col >> 10, cc = col & 1023;
        int h = cc >> 6, d = cc & 63;
        float b = bias[col];
        // fold 1/sqrt(64) * log2(e) into q so attention uses exp2 directly
        float sc = (sel == 0) ? 0.18033688011112042f : 1.0f;
        #pragma unroll
        for (int r = 0; r < 4; ++r) {
          int row = m0 + wm + mt * 16 + quad * 4 + r;  // 0..4095
          int bb = row >> 11, tt = row & 2047;
          float val = (acc[mt][nt][r] + b) * sc;
          if (sel == 2) {
            // v -> vt[bh][d][t]  (fused V transpose)
            vtp[((size_t)(bb * 16 + h) * 64 + d) * 2048 + tt] = f2bf(val);
          } else {
            qkv[(((size_t)sel * 32 + (size_t)(bb * 16 + h)) * 2048 + tt) * 64 + d] = f2bf(val);
          }
        }
      }
  }
}

// ---------- flash attention v5 (round-1/3 best-measured config) ----------
// Softmax VALU diet: HW v_cvt_pk_bf16_f32, raw v_exp_f32, setprio around MFMA.
// Pair fold-balance + XCD-aware decode: all 16 pair-blocks of a bh share one mod-8
// residue class -> same XCD L2 caches that bh's K/V (cuts HBM re-fetch ~8x).
// S^T via swapped MFMA operands; 3-buffer K/V pipeline, single barrier per tile.
__global__ __launch_bounds__(256) void attn_kernel(
    const unsigned short* __restrict__ qkv,
    const unsigned short* __restrict__ vt,
    unsigned short* __restrict__ y) {
  __shared__ unsigned short Ks[3][64 * 64];  // [key][d], swizzled chunks
  __shared__ unsigned short Vs[3][64 * 64];  // [d][key], swizzled chunks
  __shared__ unsigned short Ps[4][32][72];   // per-wave P[qrow][key]: rows 0-15 A, 16-31 B

  const int t = threadIdx.x;
  const int wave = t >> 6, lane = t & 63;
  const int L = lane & 15, quad = lane >> 4;
  // XCD-aware decode: residue class (b&7) -> XCD; 4 bh per class x 16 pairs
  const int b = blockIdx.x;
  const int bh = (b & 7) * 4 + ((b >> 3) & 3);
  const int pi = b >> 5;                // pair index 0..15
  const int tA = pi, tB = 31 - pi;      // 64-row q-tile indices
  const int rowA0 = tA * 64 + wave * 16;
  const int rowB0 = tB * 64 + wave * 16;
  const int ntiles = tB + 1;

  const unsigned short* qb  = qkv + ((size_t)bh * 2048) * 64;
  const unsigned short* kb  = qkv + ((size_t)(32 + bh) * 2048) * 64;
  const unsigned short* vtb = vt + (size_t)bh * 64 * 2048;

  // DMA per-lane constants: 8 rows (128B each) per instruction
  const int drow = lane >> 3;           // 0..7
  const int dch  = (lane & 7) ^ drow;   // source chunk (xor swizzle)
  // frag-read swizzle offsets: chunk c of row r stored at c^(r&7)
  const int fo0 = ((quad ^ (L & 7)) * 8);
  const int fo1 = (((quad + 4) ^ (L & 7)) * 8);

  // Q fragments (A/B-operand layout, direct from global, resident all kernel)
  bf16x8 qfA[2], qfB[2];
  #pragma unroll
  for (int h = 0; h < 2; ++h) {
    qfA[h] = *reinterpret_cast<const bf16x8*>(qb + (size_t)(rowA0 + L) * 64 + h * 32 + quad * 8);
    qfB[h] = *reinterpret_cast<const bf16x8*>(qb + (size_t)(rowB0 + L) * 64 + h * 32 + quad * 8);
  }

  f32x4 oA[4] = {}, oB[4] = {};
  float rsA = 0.f, rsB = 0.f;

  // prologue: stage tile 0 -> buf 0 (4 DMA instrs per wave per stage)
  {
    #pragma unroll
    for (int j = 0; j < 2; ++j) {
      int r0 = wave * 16 + j * 8;
      load_lds16(kb  + (size_t)(0 + r0 + drow) * 64 + dch * 8, &Ks[0][r0 * 64]);
      load_lds16(vtb + (size_t)(r0 + drow) * 2048 + 0 + dch * 8, &Vs[0][r0 * 64]);
    }
  }

  int buf = 0;
  for (int kt = 0; kt < ntiles; ++kt) {
    // stage kt+1 (clamped dummy on last iter keeps vmcnt accounting uniform)
    const int nkt = (kt + 1 < ntiles) ? kt + 1 : ntiles - 1;
    const int nbuf = (buf == 2) ? 0 : buf + 1;
    {
      const int kg = nkt * 64;
      #pragma unroll
      for (int j = 0; j < 2; ++j) {
        int r0 = wave * 16 + j * 8;
        load_lds16(kb  + (size_t)(kg + r0 + drow) * 64 + dch * 8, &Ks[nbuf][r0 * 64]);
        load_lds16(vtb + (size_t)(r0 + drow) * 2048 + kg + dch * 8, &Vs[nbuf][r0 * 64]);
      }
    }
    asm volatile("" ::: "memory");
    __builtin_amdgcn_s_waitcnt(0x0F74);   // vmcnt(4): tile kt's 4 DMAs done; kt+1 in flight
    __builtin_amdgcn_s_barrier();
    asm volatile("" ::: "memory");

    const bool actA = (kt <= tA);

    // ---- S^T = K Q^T : D[m=key][n=qrow] (A=K-frag, B=Q-frag) ----
    bf16x8 kf[4][2];
    #pragma unroll
    for (int nt = 0; nt < 4; ++nt) {
      kf[nt][0] = *reinterpret_cast<const bf16x8*>(&Ks[buf][(nt * 16 + L) * 64 + fo0]);
      kf[nt][1] = *reinterpret_cast<const bf16x8*>(&Ks[buf][(nt * 16 + L) * 64 + fo1]);
    }

    f32x4 sB[4] = {};
    __builtin_amdgcn_s_setprio(1);
    #pragma unroll
    for (int nt = 0; nt < 4; ++nt) {
      sB[nt] = __builtin_amdgcn_mfma_f32_16x16x32_bf16(kf[nt][0], qfB[0], sB[nt], 0, 0, 0);
      sB[nt] = __builtin_amdgcn_mfma_f32_16x16x32_bf16(kf[nt][1], qfB[1], sB[nt], 0, 0, 0);
    }
    __builtin_amdgcn_s_setprio(0);
    if (kt == tB) {  // diagonal mask: key > qrow -> -inf
      #pragma unroll
      for (int nt = 0; nt < 4; ++nt) {
        int key0 = kt * 64 + nt * 16 + quad * 4;
        int qr = rowB0 + L;
        #pragma unroll
        for (int r = 0; r < 4; ++r)
          if (key0 + r > qr) sB[nt][r] = -3.0e38f;
      }
    }
    #pragma unroll
    for (int nt = 0; nt < 4; ++nt) {
      float p0 = exp2_fast(sB[nt][0]), p1 = exp2_fast(sB[nt][1]);
      float p2 = exp2_fast(sB[nt][2]), p3 = exp2_fast(sB[nt][3]);
      rsB += (p0 + p1) + (p2 + p3);
      uint2 pk;
      pk.x = pkbf(p0, p1);
      pk.y = pkbf(p2, p3);
      *reinterpret_cast<uint2*>(&Ps[wave][16 + L][nt * 16 + quad * 4]) = pk;
    }

    if (actA) {
      f32x4 sA[4] = {};
      __builtin_amdgcn_s_setprio(1);
      #pragma unroll
      for (int nt = 0; nt < 4; ++nt) {
        sA[nt] = __builtin_amdgcn_mfma_f32_16x16x32_bf16(kf[nt][0], qfA[0], sA[nt], 0, 0, 0);
        sA[nt] = __builtin_amdgcn_mfma_f32_16x16x32_bf16(kf[nt][1], qfA[1], sA[nt], 0, 0, 0);
      }
      __builtin_amdgcn_s_setprio(0);
      if (kt == tA) {
        #pragma unroll
        for (int nt = 0; nt < 4; ++nt) {
          int key0 = kt * 64 + nt * 16 + quad * 4;
          int qr = rowA0 + L;
          #pragma unroll
          for (int r = 0; r < 4; ++r)
            if (key0 + r > qr) sA[nt][r] = -3.0e38f;
        }
      }
      #pragma unroll
      for (int nt = 0; nt < 4; ++nt) {
        float p0 = exp2_fast(sA[nt][0]), p1 = exp2_fast(sA[nt][1]);
        float p2 = exp2_fast(sA[nt][2]), p3 = exp2_fast(sA[nt][3]);
        rsA += (p0 + p1) + (p2 + p3);
        uint2 pk;
        pk.x = pkbf(p0, p1);
        pk.y = pkbf(p2, p3);
        *reinterpret_cast<uint2*>(&Ps[wave][L][nt * 16 + quad * 4]) = pk;
      }
    }

    // ---- O += P V ----  (P in A-layout directly from Ps[qrow][key])
    bf16x8 vf[4][2];
    #pragma unroll
    for (int nt = 0; nt < 4; ++nt) {
      vf[nt][0] = *reinterpret_cast<const bf16x8*>(&Vs[buf][(nt * 16 + L) * 64 + fo0]);
      vf[nt][1] = *reinterpret_cast<const bf16x8*>(&Vs[buf][(nt * 16 + L) * 64 + fo1]);
    }
    bf16x8 pb0 = *reinterpret_cast<const bf16x8*>(&Ps[wave][16 + L][quad * 8]);
    bf16x8 pb1 = *reinterpret_cast<const bf16x8*>(&Ps[wave][16 + L][32 + quad * 8]);
    __builtin_amdgcn_s_setprio(1);
    #pragma unroll
    for (int nt = 0; nt < 4; ++nt) {
      oB[nt] = __builtin_amdgcn_mfma_f32_16x16x32_bf16(pb0, vf[nt][0], oB[nt], 0, 0, 0);
      oB[nt] = __builtin_amdgcn_mfma_f32_16x16x32_bf16(pb1, vf[nt][1], oB[nt], 0, 0, 0);
    }
    __builtin_amdgcn_s_setprio(0);
    if (actA) {
      bf16x8 pa0 = *reinterpret_cast<const bf16x8*>(&Ps[wave][L][quad * 8]);
      bf16x8 pa1 = *reinterpret_cast<const bf16x8*>(&Ps[wave][L][32 + quad * 8]);
      __builtin_amdgcn_s_setprio(1);
      #pragma unroll
      for (int nt = 0; nt < 4; ++nt) {
        oA[nt] = __builtin_amdgcn_mfma_f32_16x16x32_bf16(pa0, vf[nt][0], oA[nt], 0, 0, 0);
        oA[nt] = __builtin_amdgcn_mfma_f32_16x16x32_bf16(pa1, vf[nt][1], oA[nt], 0, 0, 0);
      }
      __builtin_amdgcn_s_setprio(0);
    }
    buf = nbuf;
  }

  // ---- epilogue: reduce l across quads (rows live on L), fetch per-output-row via shfl ----
  float a = rsA; a += __shfl_xor(a, 16, 64); a += __shfl_xor(a, 32, 64);
  float b2 = rsB; b2 += __shfl_xor(b2, 16, 64); b2 += __shfl_xor(b2, 32, 64);
  float invA[4], invB[4];
  #pragma unroll
  for (int r = 0; r < 4; ++r) {
    invA[r] = 1.0f / __shfl(a, quad * 4 + r, 64);
    invB[r] = 1.0f / __shfl(b2, quad * 4 + r, 64);
  }
  const int bb = bh >> 4, hh = bh & 15;
  #pragma unroll
  for (int nt = 0; nt < 4; ++nt)
    #pragma unroll
    for (int r = 0; r < 4; ++r) {
      int rA = rowA0 + quad * 4 + r;
      int rB = rowB0 + quad * 4 + r;
      int col = hh * 64 + nt * 16 + L;
      y[((size_t)bb * 2048 + rA) * 1024 + col] = f2bf(oA[nt][r] * invA[r]);
      y[((size_t)bb * 2048 + rB) * 1024 + col] = f2bf(oB[nt][r] * invB[r]);
    }
  // drain outstanding dummy DMAs before LDS dealloc at wave end
  __builtin_amdgcn_s_waitcnt(0);
}

extern "C" void kernel_launch(void* const* d_in, const int* in_sizes, int n_in,
                              void* d_out, int out_size, void* d_ws, size_t ws_size,
                              hipStream_t stream) {
  const float* x      = (const float*)d_in[0];  // [2,2048,1024]
  const float* w_attn = (const float*)d_in[1];  // [1024,3072]
  const float* b_attn = (const float*)d_in[2];  // [3072]
  const float* w_proj = (const float*)d_in[3];  // [1024,1024]
  const float* b_proj = (const float*)d_in[4];  // [1024]
  float* out = (float*)d_out;                   // [2,2048,1024] fp32

  unsigned short* ws = (unsigned short*)d_ws;
  unsigned short* xb     = ws;                    //  4194304 [4096,1024]
  unsigned short* wattnT = xb + 4194304;          //  3145728 [3072,1024]
  unsigned short* wprojT = wattnT + 3145728;      //  1048576 [1024,1024]
  unsigned short* qkv    = wprojT + 1048576;      // 12582912 [3][32][2048][64] (v unused)
  unsigned short* yb     = qkv + 12582912;        //  4194304 [4096,1024]
  unsigned short* vt     = yb + 4194304;          //  4194304 [32][64][2048]

  // fused prep: cast x + transpose both weight matrices (one launch)
  prep_kernel<<<8192, 256, 0, stream>>>(x, w_attn, w_proj, xb, wattnT, wprojT);

  // QKV: M=4096, N=3072, K=1024; 128^2 tiles, grid (24,32) LINEAR decode
  // (round-3 proven optimum: 45.5us; linear decode preserves A-panel sharing)
  gemm_bt_kernel<128, 128><<<dim3(24, 32), 256, 0, stream>>>(xb, wattnT, b_attn, qkv, vt, 4096, 3072, 1024, 1);
  // attention (fold-balanced, XCD-grouped, 3-buffer pipelined)
  attn_kernel<<<dim3(512), 256, 0, stream>>>(qkv, vt, yb);
  // proj: M=4096, N=1024, K=1024; 64^2 tiles, grid (16,64) linear (round-3 config)
  gemm_bt_kernel<64, 64><<<dim3(16, 64), 256, 0, stream>>>(yb, wprojT, b_proj, out, nullptr, 4096, 1024, 1024, 0);
}